// Round 9
// baseline (632.231 us; speedup 1.0000x reference)
//
#include <hip/hip_runtime.h>
#include <hip/hip_fp8.h>
#include <math.h>

#define NND   32768
#define HIDD  128
#define NHEAD 64
#define BSS   512
#define OUTC  3
#define NBLK  256   // persistent-kernel grid: 1 block/CU, guaranteed co-resident

typedef _Float16 half_t;
typedef __attribute__((ext_vector_type(8))) _Float16 half8;
typedef __attribute__((ext_vector_type(4))) float f32x4;

__device__ __forceinline__ unsigned enc_fp8x4(float a, float b, float c, float d) {
    __hip_fp8x4_e4m3 q(make_float4(a, b, c, d));
    return (unsigned)q.__x;
}
__device__ __forceinline__ float4 dec_fp8x4(unsigned v) {
    __hip_fp8x4_e4m3 t; t.__x = (__hip_fp8x4_storage_t)v;
    return (float4)t;
}

// generation-based grid barrier (cnt/gen zeroed by host memset before launch)
__device__ __forceinline__ void gridsync(int* cnt, int* gen) {
    __syncthreads();
    if (threadIdx.x == 0) {
        __threadfence();
        int my = __hip_atomic_load(gen, __ATOMIC_ACQUIRE, __HIP_MEMORY_SCOPE_AGENT);
        int old = __hip_atomic_fetch_add(cnt, 1, __ATOMIC_ACQ_REL, __HIP_MEMORY_SCOPE_AGENT);
        if (old == NBLK - 1) {
            __hip_atomic_store(cnt, 0, __ATOMIC_RELAXED, __HIP_MEMORY_SCOPE_AGENT);
            __hip_atomic_store(gen, my + 1, __ATOMIC_RELEASE, __HIP_MEMORY_SCOPE_AGENT);
        } else {
            while (__hip_atomic_load(gen, __ATOMIC_ACQUIRE, __HIP_MEMORY_SCOPE_AGENT) == my)
                __builtin_amdgcn_s_sleep(2);
        }
        __threadfence();
    }
    __syncthreads();
}

// ---------------- prep: weight transposes, w_s/w_d GEMVs, x cast, edge count ----------
__global__ __launch_bounds__(256) void prep_kernel(const float* __restrict__ W0,
        const float* __restrict__ W_res, const float* __restrict__ W1p,
        const float* __restrict__ as0, const float* __restrict__ ad0,
        const float* __restrict__ as_res, const float* __restrict__ ad_res,
        const float* __restrict__ x, const int* __restrict__ ei, int E,
        half_t* __restrict__ Wh, half_t* __restrict__ W1h, half_t* __restrict__ W0t,
        float* __restrict__ wvec, half_t* __restrict__ xh,
        int* __restrict__ counts, int* __restrict__ rank) {
    int b = blockIdx.x, tid = threadIdx.x;
    if (b < 64) {
        __shared__ float tile[32][33];
        int l = b >> 4, t = b & 15;
        int k0 = (t >> 2) * 32, n0 = (t & 3) * 32;
        const float* src = W_res + (size_t)l * 128 * 128;
        half_t* dst = Wh + (size_t)l * 128 * 128;
        int c = tid & 31, r0 = tid >> 5;
#pragma unroll
        for (int i = 0; i < 4; ++i) tile[r0 + i * 8][c] = src[(size_t)(k0 + r0 + i * 8) * 128 + n0 + c];
        __syncthreads();
#pragma unroll
        for (int i = 0; i < 4; ++i) dst[(size_t)(n0 + r0 + i * 8) * 128 + k0 + c] = (half_t)tile[c][r0 + i * 8];
    } else if (b < 576) {
        __shared__ float tile[32][33];
        int bb = b - 64, head = bb >> 3, t = bb & 7;
        int k0 = (t >> 1) * 32, n0 = (t & 1) * 32;
        const float* src = W1p + (size_t)head * 128 * 64;
        half_t* dst = W1h + (size_t)head * 64 * 128;
        int c = tid & 31, r0 = tid >> 5;
#pragma unroll
        for (int i = 0; i < 4; ++i) tile[r0 + i * 8][c] = src[(size_t)(k0 + r0 + i * 8) * 64 + n0 + c];
        __syncthreads();
#pragma unroll
        for (int i = 0; i < 4; ++i) dst[(size_t)(n0 + r0 + i * 8) * 128 + k0 + c] = (half_t)tile[c][r0 + i * 8];
    } else if (b == 576) {
        __shared__ float t0[32][129];
        for (int i = tid; i < 4096; i += 256) t0[i >> 7][i & 127] = W0[i];
        __syncthreads();
        for (int i = tid; i < 4096; i += 256) { int n = i >> 5, k = i & 31; W0t[n * 32 + k] = (half_t)t0[k][n]; }
    } else if (b == 577) {
        for (int task = tid; task < 1088; task += 256) {
            const float* row; const float* att; int slot, sd;
            if (task < 64) {
                int k = task >> 1; sd = task & 1;
                row = W0 + k * 128; att = sd ? ad0 : as0; slot = k;
            } else {
                int tt = task - 64; int l = 1 + tt / 256; int r = tt % 256;
                int k = r >> 1; sd = r & 1;
                row = W_res + (size_t)(l - 1) * 16384 + k * 128;
                att = (sd ? ad_res : as_res) + (l - 1) * 128;
                slot = l * 128 + k;
            }
            float s = 0.f;
            for (int n = 0; n < 128; ++n) s += row[n] * att[n];
            (sd ? wvec + 640 : wvec)[slot] = s;
        }
    } else if (b < 1090) {
        int b2 = b - 578;
        const float* xs = x + (size_t)b2 * 64 * 32;
        half_t* xd = xh + (size_t)b2 * 64 * 32;
        for (int i = tid; i < 1024; i += 256) {
            float2 v = ((const float2*)xs)[i];
            union { unsigned u; half_t h[2]; } cv;
            cv.h[0] = (half_t)v.x; cv.h[1] = (half_t)v.y;
            ((unsigned*)xd)[i] = cv.u;
        }
    } else {
        int j = (b - 1090) * 256 + tid;
        int Etot = E + NND;
        if (j >= Etot) return;
        int dst = (j < E) ? ei[E + j] : (j - E);
        rank[j] = atomicAdd(&counts[dst], 1);
    }
}

__global__ __launch_bounds__(1024) void scan_kernel(const int* __restrict__ counts,
                                                    int* __restrict__ off) {
    __shared__ int sums[1024];
    int tid = threadIdx.x;
    int base = tid * 32;
    int tmp[32];
    int run = 0;
#pragma unroll
    for (int i = 0; i < 8; ++i) {
        int4 c4 = *(const int4*)&counts[base + i * 4];
        tmp[i*4+0] = run; run += c4.x;
        tmp[i*4+1] = run; run += c4.y;
        tmp[i*4+2] = run; run += c4.z;
        tmp[i*4+3] = run; run += c4.w;
    }
    sums[tid] = run;
    __syncthreads();
    for (int d = 1; d < 1024; d <<= 1) {
        int v = (tid >= d) ? sums[tid - d] : 0;
        __syncthreads();
        sums[tid] += v;
        __syncthreads();
    }
    int ebase = (tid == 0) ? 0 : sums[tid - 1];
#pragma unroll
    for (int i = 0; i < 32; ++i) off[base + i] = ebase + tmp[i];
    if (tid == 1023) off[NND] = sums[1023];
}

__global__ __launch_bounds__(256) void fill_a0_kernel(const int* __restrict__ ei, int E, int egrid,
        const int* __restrict__ off, const int* __restrict__ rank, int* __restrict__ csr_src,
        const half_t* __restrict__ xh, const float* __restrict__ wvec,
        float* __restrict__ a_s, float* __restrict__ a_d) {
    int b = blockIdx.x, tid = threadIdx.x;
    if (b < egrid) {
        int j = b * 256 + tid;
        int Etot = E + NND;
        if (j >= Etot) return;
        int src, dst;
        if (j < E) { src = ei[j]; dst = ei[E + j]; }
        else       { src = j - E; dst = j - E; }
        csr_src[off[dst] + rank[j]] = src;
    } else {
        __shared__ float ws0[32], wd0[32];
        if (tid < 32) { ws0[tid] = wvec[tid]; wd0[tid] = wvec[640 + tid]; }
        __syncthreads();
        int g = (b - egrid) * 256 + tid;
        int node = g >> 2, part = g & 3;
        half8 xv = *(const half8*)&xh[(size_t)node * 32 + part * 8];
        float s = 0.f, d2 = 0.f;
#pragma unroll
        for (int j = 0; j < 8; ++j) { float f = (float)xv[j]; s += f * ws0[part * 8 + j]; d2 += f * wd0[part * 8 + j]; }
        s += __shfl_xor(s, 1); s += __shfl_xor(s, 2);
        d2 += __shfl_xor(d2, 1); d2 += __shfl_xor(d2, 2);
        if (part == 0) { a_s[node] = s; a_d[node] = d2; }
    }
}

// ================= ONE persistent kernel for all 5 layers + predictor =================
__global__ __launch_bounds__(1024, 4) void layers_kernel(
        const half_t* __restrict__ xh,
        const int* __restrict__ csr_src, const int* __restrict__ off,
        const half_t* __restrict__ W0t, const half_t* __restrict__ Wh,
        const float* __restrict__ bias0, const float* __restrict__ b_res,
        const float* __restrict__ gamma, const float* __restrict__ beta,
        const float* __restrict__ wvec,
        half_t* __restrict__ Pbuf, half_t* __restrict__ Hh,
        unsigned char* __restrict__ Th8A, unsigned char* __restrict__ Th8B,
        float* __restrict__ as0, float* __restrict__ ad0,
        float* __restrict__ as1, float* __restrict__ ad1,
        const half_t* __restrict__ W1h, const float* __restrict__ W2p,
        float* __restrict__ out, int* __restrict__ bar) {
    __shared__ __align__(16) char smem[65536];
    half_t* Wt = (half_t*)smem;              // res: [128][128] swizzled; l0: [128][40]
    half_t* Ps = (half_t*)(smem + 32768);    // res: [128][128] swizzled
    half_t* Ps40 = (half_t*)(smem + 16384);  // l0: [128][40]
    float*  vv = (float*)smem;               // epilogue overlay [64][128]
    int* cnt = bar; int* gen = bar + 1;
    const int tid = threadIdx.x;
    const int w = tid >> 6, lane = tid & 63, q = lane >> 4, r15 = lane & 15;
    const int gw = blockIdx.x * 16 + w;
    const int n0 = blockIdx.x * 128;
    const int nl = tid >> 4, sub = tid & 15;

    // ---------- phase: agg0 (grid-stride waves, gather xh 32ch) -> Pbuf[d][32] ----------
    for (int d = gw; d < NND; d += NBLK * 16) {
        int beg = off[d], end = off[d + 1];
        float adv = ad0[d];
        float pz = 0.f, a0 = 0.f, a1 = 0.f;
        for (int base = beg; base < end; base += 64) {
            int j = base + lane;
            int s = 0; float p = 0.f;
            if (j < end) {
                s = csr_src[j];
                float tt = as0[s] + adv;
                tt = (tt > 0.f) ? tt : 0.2f * tt;
                p = __expf(tt);
            }
            pz += p;
            int cntc = end - base; if (cntc > 64) cntc = 64;
            int full = cntc & ~15;
            int k4 = 0;
            for (; k4 < full; k4 += 16) {
                int s0 = __shfl(s, k4 + q);      float p0 = __shfl(p, k4 + q);
                int s1 = __shfl(s, k4 + 4 + q);  float p1 = __shfl(p, k4 + 4 + q);
                int s2 = __shfl(s, k4 + 8 + q);  float p2 = __shfl(p, k4 + 8 + q);
                int s3 = __shfl(s, k4 + 12 + q); float p3 = __shfl(p, k4 + 12 + q);
                union { unsigned u; half_t h[2]; } u0, u1, u2, u3;
                u0.u = *(const unsigned*)&xh[(size_t)s0 * 32 + r15 * 2];
                u1.u = *(const unsigned*)&xh[(size_t)s1 * 32 + r15 * 2];
                u2.u = *(const unsigned*)&xh[(size_t)s2 * 32 + r15 * 2];
                u3.u = *(const unsigned*)&xh[(size_t)s3 * 32 + r15 * 2];
                a0 += p0 * (float)u0.h[0] + p1 * (float)u1.h[0] + p2 * (float)u2.h[0] + p3 * (float)u3.h[0];
                a1 += p0 * (float)u0.h[1] + p1 * (float)u1.h[1] + p2 * (float)u2.h[1] + p3 * (float)u3.h[1];
            }
            for (; k4 < cntc; k4 += 4) {
                int s0 = __shfl(s, k4 + q); float p0 = __shfl(p, k4 + q);
                union { unsigned u; half_t h[2]; } u0;
                u0.u = *(const unsigned*)&xh[(size_t)s0 * 32 + r15 * 2];
                a0 += p0 * (float)u0.h[0]; a1 += p0 * (float)u0.h[1];
            }
        }
#pragma unroll
        for (int o = 32; o; o >>= 1) pz += __shfl_xor(pz, o);
        a0 += __shfl_xor(a0, 16); a0 += __shfl_xor(a0, 32);
        a1 += __shfl_xor(a1, 16); a1 += __shfl_xor(a1, 32);
        if (q == 0) {
            float inv = 1.f / (pz + 1e-16f);
            union { unsigned u; half_t h[2]; } uu;
            uu.h[0] = (half_t)(a0 * inv); uu.h[1] = (half_t)(a1 * inv);
            *(unsigned*)&Pbuf[(size_t)d * 32 + r15 * 2] = uu.u;
        }
    }
    gridsync(cnt, gen);

    // ---------- phase: gemm0 on block tile [n0, n0+128), K=32 ----------
    {
        for (int i = tid; i < 512; i += 1024) {   // Wt0 [128][40]
            int n = i >> 2, c = i & 3;
            *(int4*)&Wt[n * 40 + c * 8] = *(const int4*)&W0t[(size_t)n * 32 + c * 8];
        }
        for (int i = tid; i < 512; i += 1024) {   // Ps40 from Pbuf
            int n = i >> 2, c = i & 3;
            *(int4*)&Ps40[n * 40 + c * 8] = *(const int4*)&Pbuf[(size_t)(n0 + n) * 32 + c * 8];
        }
        __syncthreads();
        const int rt = w >> 1, cb = (w & 1) * 4;
        half8 af = *(const half8*)&Ps40[(rt * 16 + r15) * 40 + q * 8];
        f32x4 c4[4];
#pragma unroll
        for (int ct = 0; ct < 4; ++ct) {
            f32x4 c = {0.f, 0.f, 0.f, 0.f};
            half8 bf = *(const half8*)&Wt[((cb + ct) * 16 + r15) * 40 + q * 8];
            c = __builtin_amdgcn_mfma_f32_16x16x32_f16(af, bf, c, 0, 0, 0);
            c4[ct] = c;
        }
        __syncthreads();
        const float* wsn = wvec + 128;
        const float* wdn = wvec + 640 + 128;
#pragma unroll
        for (int chunk = 0; chunk < 2; ++chunk) {
            if ((rt >> 2) == chunk) {
                int rb = (rt & 3) * 16 + q * 4;
#pragma unroll
                for (int ct = 0; ct < 4; ++ct)
#pragma unroll
                    for (int r = 0; r < 4; ++r)
                        vv[(rb + r) * 128 + (cb + ct) * 16 + r15] = c4[ct][r];
            }
            __syncthreads();
            int node = n0 + chunk * 64 + nl;
            float v8[8];
#pragma unroll
            for (int j = 0; j < 8; ++j) v8[j] = fmaxf(vv[nl * 128 + sub * 8 + j] + bias0[sub * 8 + j], 0.f);
            union { int4 i4; half_t h[8]; } hw;
#pragma unroll
            for (int j = 0; j < 8; ++j) hw.h[j] = (half_t)v8[j];
            *(int4*)&Hh[(size_t)node * HIDD + sub * 8] = hw.i4;
            float sum = 0.f;
#pragma unroll
            for (int j = 0; j < 8; ++j) sum += v8[j];
#pragma unroll
            for (int o = 8; o; o >>= 1) sum += __shfl_xor(sum, o);
            float mu = sum * (1.f / HIDD);
            float var = 0.f;
#pragma unroll
            for (int j = 0; j < 8; ++j) { float dx = v8[j] - mu; var += dx * dx; }
#pragma unroll
            for (int o = 8; o; o >>= 1) var += __shfl_xor(var, o);
            float rs = rsqrtf(var * (1.f / HIDD) + 1e-5f);
            float tt[8]; float asn = 0.f, adn = 0.f;
#pragma unroll
            for (int j = 0; j < 8; ++j) {
                float t = fmaxf((v8[j] - mu) * rs * gamma[sub * 8 + j] + beta[sub * 8 + j], 0.f);
                tt[j] = t; asn += t * wsn[sub * 8 + j]; adn += t * wdn[sub * 8 + j];
            }
            uint2 tw;
            tw.x = enc_fp8x4(tt[0], tt[1], tt[2], tt[3]);
            tw.y = enc_fp8x4(tt[4], tt[5], tt[6], tt[7]);
            *(uint2*)&Th8A[(size_t)node * HIDD + sub * 8] = tw;
#pragma unroll
            for (int o = 8; o; o >>= 1) { asn += __shfl_xor(asn, o); adn += __shfl_xor(adn, o); }
            if (sub == 0) { as1[node] = asn; ad1[node] = adn; }
            __syncthreads();
        }
    }
    gridsync(cnt, gen);

    // ---------- 4 residual layers ----------
    for (int L = 0; L < 4; ++L) {
        const unsigned char* Fin = (L & 1) ? Th8B : Th8A;
        unsigned char* Fout      = (L & 1) ? Th8A : Th8B;
        const float* asv = (L & 1) ? as0 : as1;
        const float* adv_ = (L & 1) ? ad0 : ad1;
        float* aso = (L & 1) ? as1 : as0;
        float* ado = (L & 1) ? ad1 : ad0;
        const bool last = (L == 3);
        const float* bia = b_res + L * HIDD;
        const float* gam = gamma + (last ? 0 : (L + 1)) * HIDD;
        const float* bet = beta + (last ? 0 : (L + 1)) * HIDD;
        const float* wsn = wvec + (L + 2) * 128;
        const float* wdn = wvec + 640 + (L + 2) * 128;
        const half_t* Whl = Wh + (size_t)L * 16384;

        // ---- agg phase (grid-stride waves, fp8 gather) -> Pbuf[d][128] ----
        for (int d = gw; d < NND; d += NBLK * 16) {
            int beg = off[d], end = off[d + 1];
            float adv2 = adv_[d];
            float pz = 0.f;
            float acc[8] = {0.f,0.f,0.f,0.f,0.f,0.f,0.f,0.f};
            for (int base = beg; base < end; base += 64) {
                int j = base + lane;
                int s = 0; float p = 0.f;
                if (j < end) {
                    s = csr_src[j];
                    float tt = asv[s] + adv2;
                    tt = (tt > 0.f) ? tt : 0.2f * tt;
                    p = __expf(tt);
                }
                pz += p;
                int cntc = end - base; if (cntc > 64) cntc = 64;
                int full = cntc & ~15;
                int k4 = 0;
                for (; k4 < full; k4 += 16) {
                    int s0 = __shfl(s, k4 + q);      float p0 = __shfl(p, k4 + q);
                    int s1 = __shfl(s, k4 + 4 + q);  float p1 = __shfl(p, k4 + 4 + q);
                    int s2 = __shfl(s, k4 + 8 + q);  float p2 = __shfl(p, k4 + 8 + q);
                    int s3 = __shfl(s, k4 + 12 + q); float p3 = __shfl(p, k4 + 12 + q);
                    uint2 r0 = *(const uint2*)&Fin[(size_t)s0 * HIDD + r15 * 8];
                    uint2 r1 = *(const uint2*)&Fin[(size_t)s1 * HIDD + r15 * 8];
                    uint2 r2 = *(const uint2*)&Fin[(size_t)s2 * HIDD + r15 * 8];
                    uint2 r3 = *(const uint2*)&Fin[(size_t)s3 * HIDD + r15 * 8];
                    float4 f;
                    f = dec_fp8x4(r0.x); acc[0]+=p0*f.x; acc[1]+=p0*f.y; acc[2]+=p0*f.z; acc[3]+=p0*f.w;
                    f = dec_fp8x4(r0.y); acc[4]+=p0*f.x; acc[5]+=p0*f.y; acc[6]+=p0*f.z; acc[7]+=p0*f.w;
                    f = dec_fp8x4(r1.x); acc[0]+=p1*f.x; acc[1]+=p1*f.y; acc[2]+=p1*f.z; acc[3]+=p1*f.w;
                    f = dec_fp8x4(r1.y); acc[4]+=p1*f.x; acc[5]+=p1*f.y; acc[6]+=p1*f.z; acc[7]+=p1*f.w;
                    f = dec_fp8x4(r2.x); acc[0]+=p2*f.x; acc[1]+=p2*f.y; acc[2]+=p2*f.z; acc[3]+=p2*f.w;
                    f = dec_fp8x4(r2.y); acc[4]+=p2*f.x; acc[5]+=p2*f.y; acc[6]+=p2*f.z; acc[7]+=p2*f.w;
                    f = dec_fp8x4(r3.x); acc[0]+=p3*f.x; acc[1]+=p3*f.y; acc[2]+=p3*f.z; acc[3]+=p3*f.w;
                    f = dec_fp8x4(r3.y); acc[4]+=p3*f.x; acc[5]+=p3*f.y; acc[6]+=p3*f.z; acc[7]+=p3*f.w;
                }
                for (; k4 < cntc; k4 += 4) {
                    int s0 = __shfl(s, k4 + q); float p0 = __shfl(p, k4 + q);
                    uint2 r0 = *(const uint2*)&Fin[(size_t)s0 * HIDD + r15 * 8];
                    float4 f;
                    f = dec_fp8x4(r0.x); acc[0]+=p0*f.x; acc[1]+=p0*f.y; acc[2]+=p0*f.z; acc[3]+=p0*f.w;
                    f = dec_fp8x4(r0.y); acc[4]+=p0*f.x; acc[5]+=p0*f.y; acc[6]+=p0*f.z; acc[7]+=p0*f.w;
                }
            }
#pragma unroll
            for (int o = 32; o; o >>= 1) pz += __shfl_xor(pz, o);
#pragma unroll
            for (int i = 0; i < 8; ++i) {
                acc[i] += __shfl_xor(acc[i], 16);
                acc[i] += __shfl_xor(acc[i], 32);
            }
            if (q == 0) {
                float inv = 1.f / (pz + 1e-16f);
                union { int4 v; half_t hh[8]; } u;
#pragma unroll
                for (int i = 0; i < 8; ++i) u.hh[i] = (half_t)(acc[i] * inv);
                *(int4*)&Pbuf[(size_t)d * HIDD + r15 * 8] = u.v;
            }
        }
        gridsync(cnt, gen);

        // ---- gemm phase on block tile, K=128 ----
        for (int i = tid; i < 2048; i += 1024) {   // Wt swizzled
            int n = i >> 4, c = i & 15;
            *(int4*)&Wt[n * 128 + ((c ^ (n & 15)) * 8)] = *(const int4*)&Whl[(size_t)n * 128 + c * 8];
        }
        for (int i = tid; i < 2048; i += 1024) {   // Ps swizzled from Pbuf
            int n = i >> 4, c = i & 15;
            *(int4*)&Ps[n * 128 + ((c ^ (n & 15)) * 8)] = *(const int4*)&Pbuf[(size_t)(n0 + n) * HIDD + c * 8];
        }
        __syncthreads();
        const int rt = w >> 1, cb = (w & 1) * 4;
        half8 af[4];
#pragma unroll
        for (int s = 0; s < 4; ++s) {
            int n = rt * 16 + r15, idx = s * 4 + q;
            af[s] = *(const half8*)&Ps[n * 128 + ((idx ^ (n & 15)) * 8)];
        }
        f32x4 c4[4];
#pragma unroll
        for (int ct = 0; ct < 4; ++ct) {
            f32x4 c = {0.f, 0.f, 0.f, 0.f};
            int n = (cb + ct) * 16 + r15;
#pragma unroll
            for (int s = 0; s < 4; ++s) {
                int idx = s * 4 + q;
                half8 bf = *(const half8*)&Wt[n * 128 + ((idx ^ (n & 15)) * 8)];
                c = __builtin_amdgcn_mfma_f32_16x16x32_f16(af[s], bf, c, 0, 0, 0);
            }
            c4[ct] = c;
        }
        __syncthreads();
#pragma unroll
        for (int chunk = 0; chunk < 2; ++chunk) {
            if ((rt >> 2) == chunk) {
                int rb = (rt & 3) * 16 + q * 4;
#pragma unroll
                for (int ct = 0; ct < 4; ++ct)
#pragma unroll
                    for (int r = 0; r < 4; ++r)
                        vv[(rb + r) * 128 + (cb + ct) * 16 + r15] = c4[ct][r];
            }
            __syncthreads();
            int node = n0 + chunk * 64 + nl;
            float v8[8];
            half8 hold = *(const half8*)&Hh[(size_t)node * HIDD + sub * 8];
#pragma unroll
            for (int j = 0; j < 8; ++j) v8[j] = vv[nl * 128 + sub * 8 + j] + bia[sub * 8 + j] + (float)hold[j];
            if (!last) {
                union { int4 i4; half_t h[8]; } hw;
#pragma unroll
                for (int j = 0; j < 8; ++j) hw.h[j] = (half_t)v8[j];
                *(int4*)&Hh[(size_t)node * HIDD + sub * 8] = hw.i4;
            }
            float sum = 0.f;
#pragma unroll
            for (int j = 0; j < 8; ++j) sum += v8[j];
#pragma unroll
            for (int o = 8; o; o >>= 1) sum += __shfl_xor(sum, o);
            float mu = sum * (1.f / HIDD);
            float var = 0.f;
#pragma unroll
            for (int j = 0; j < 8; ++j) { float dx = v8[j] - mu; var += dx * dx; }
#pragma unroll
            for (int o = 8; o; o >>= 1) var += __shfl_xor(var, o);
            float rs = rsqrtf(var * (1.f / HIDD) + 1e-5f);
            if (!last) {
                float tt[8]; float asn = 0.f, adn = 0.f;
#pragma unroll
                for (int j = 0; j < 8; ++j) {
                    float t = fmaxf((v8[j] - mu) * rs * gam[sub * 8 + j] + bet[sub * 8 + j], 0.f);
                    tt[j] = t; asn += t * wsn[sub * 8 + j]; adn += t * wdn[sub * 8 + j];
                }
                uint2 tw;
                tw.x = enc_fp8x4(tt[0], tt[1], tt[2], tt[3]);
                tw.y = enc_fp8x4(tt[4], tt[5], tt[6], tt[7]);
                *(uint2*)&Fout[(size_t)node * HIDD + sub * 8] = tw;
#pragma unroll
                for (int o = 8; o; o >>= 1) { asn += __shfl_xor(asn, o); adn += __shfl_xor(adn, o); }
                if (sub == 0) { aso[node] = asn; ado[node] = adn; }
            } else {
                union { int4 i4; half_t h[8]; } twr;
#pragma unroll
                for (int j = 0; j < 8; ++j)
                    twr.h[j] = (half_t)fmaxf((v8[j] - mu) * rs * gam[sub * 8 + j] + bet[sub * 8 + j], 0.f);
                int g = chunk * 64 + nl;
                *(int4*)&Ps[g * 128 + ((sub ^ (g & 15)) * 8)] = twr.i4;
            }
            __syncthreads();
        }
        if (!last) gridsync(cnt, gen);
    }

    // ---------- predictor on final T tile (in Ps), waves 0..7 ----------
    if (w < 8) {
        int head = n0 >> 9;
        const half_t* W1g = W1h + (size_t)head * 64 * 128;
        half8 pa[4];
#pragma unroll
        for (int s = 0; s < 4; ++s) {
            int n = w * 16 + r15, idx = s * 4 + q;
            pa[s] = *(const half8*)&Ps[n * 128 + ((idx ^ (n & 15)) * 8)];
        }
        float lg[3][4];
#pragma unroll
        for (int o = 0; o < 3; ++o)
#pragma unroll
            for (int r = 0; r < 4; ++r) lg[o][r] = 0.f;
#pragma unroll
        for (int ct2 = 0; ct2 < 4; ++ct2) {
            int n2 = ct2 * 16 + r15;
            f32x4 c = {0.f, 0.f, 0.f, 0.f};
#pragma unroll
            for (int s = 0; s < 4; ++s) {
                half8 bf = *(const half8*)&W1g[(size_t)n2 * 128 + s * 32 + q * 8];
                c = __builtin_amdgcn_mfma_f32_16x16x32_f16(pa[s], bf, c, 0, 0, 0);
            }
            float w2a = W2p[(size_t)head * 192 + n2 * 3 + 0];
            float w2b = W2p[(size_t)head * 192 + n2 * 3 + 1];
            float w2c = W2p[(size_t)head * 192 + n2 * 3 + 2];
#pragma unroll
            for (int r = 0; r < 4; ++r) {
                float t = fmaxf(c[r], 0.f);
                lg[0][r] += t * w2a;
                lg[1][r] += t * w2b;
                lg[2][r] += t * w2c;
            }
        }
#pragma unroll
        for (int o = 8; o; o >>= 1)
#pragma unroll
            for (int oo = 0; oo < 3; ++oo)
#pragma unroll
                for (int r = 0; r < 4; ++r) lg[oo][r] += __shfl_xor(lg[oo][r], o);
        if (r15 == 0) {
            int nodeD = n0 + w * 16 + q * 4;
#pragma unroll
            for (int r = 0; r < 4; ++r) {
                float l0 = lg[0][r], l1 = lg[1][r], l2 = lg[2][r];
                float mx = fmaxf(l0, fmaxf(l1, l2));
                float e0 = __expf(l0 - mx), e1 = __expf(l1 - mx), e2 = __expf(l2 - mx);
                float inv = 1.f / (e0 + e1 + e2);
                float* op = out + (size_t)(nodeD + r) * OUTC;
                op[0] = e0 * inv; op[1] = e1 * inv; op[2] = e2 * inv;
            }
        }
    }
}

extern "C" void kernel_launch(void* const* d_in, const int* in_sizes, int n_in,
                              void* d_out, int out_size, void* d_ws, size_t ws_size,
                              hipStream_t stream) {
    const float* x        = (const float*)d_in[0];
    const int*   ei       = (const int*)d_in[1];
    const float* W0       = (const float*)d_in[2];
    const float* att_src0 = (const float*)d_in[3];
    const float* att_dst0 = (const float*)d_in[4];
    const float* bias0    = (const float*)d_in[5];
    const float* W_res    = (const float*)d_in[6];
    const float* as_res   = (const float*)d_in[7];
    const float* ad_res   = (const float*)d_in[8];
    const float* b_res    = (const float*)d_in[9];
    const float* gamma    = (const float*)d_in[10];
    const float* beta     = (const float*)d_in[11];
    const float* W1p      = (const float*)d_in[12];
    const float* W2p      = (const float*)d_in[13];
    float* out = (float*)d_out;

    int E = in_sizes[1] / 2;
    int Etot = E + NND;

    char* p = (char*)d_ws;
    auto alloc = [&](size_t bytes) { void* r = (void*)p; p += (bytes + 255) & ~(size_t)255; return r; };
    int*    bar     = (int*)alloc(256);                 // barrier cnt/gen (memset'd with counts)
    int*    counts  = (int*)alloc((size_t)NND * 4);
    int*    off     = (int*)alloc((size_t)(NND + 1) * 4);
    int*    rank    = (int*)alloc((size_t)Etot * 4);
    int*    csr_src = (int*)alloc((size_t)Etot * 4);
    half_t* xh      = (half_t*)alloc((size_t)NND * 32 * 2);
    half_t* Pbuf    = (half_t*)alloc((size_t)NND * HIDD * 2);
    unsigned char* Th8A = (unsigned char*)alloc((size_t)NND * HIDD);
    unsigned char* Th8B = (unsigned char*)alloc((size_t)NND * HIDD);
    half_t* Hh      = (half_t*)alloc((size_t)NND * HIDD * 2);
    float*  a_s0    = (float*)alloc((size_t)NND * 4);
    float*  a_d0    = (float*)alloc((size_t)NND * 4);
    float*  a_s1    = (float*)alloc((size_t)NND * 4);
    float*  a_d1    = (float*)alloc((size_t)NND * 4);
    half_t* Wh      = (half_t*)alloc((size_t)4 * HIDD * HIDD * 2);
    half_t* W1h     = (half_t*)alloc((size_t)NHEAD * 64 * HIDD * 2);
    half_t* W0t     = (half_t*)alloc((size_t)HIDD * 32 * 2);
    float*  wvec    = (float*)alloc((size_t)1280 * 4);

    int egrid = (Etot + 255) / 256;

    // one memset covers barrier header + counts (contiguous)
    hipMemsetAsync(bar, 0, 256 + (size_t)NND * 4, stream);
    prep_kernel<<<1090 + egrid, 256, 0, stream>>>(W0, W_res, W1p, att_src0, att_dst0,
        as_res, ad_res, x, ei, E, Wh, W1h, W0t, wvec, xh, counts, rank);
    scan_kernel<<<1, 1024, 0, stream>>>(counts, off);
    fill_a0_kernel<<<egrid + 512, 256, 0, stream>>>(ei, E, egrid, off, rank, csr_src,
                                                    xh, wvec, a_s0, a_d0);

    // all 5 layers + predictor in one persistent kernel (9 internal grid syncs)
    layers_kernel<<<NBLK, 1024, 0, stream>>>(xh, csr_src, off, W0t, Wh, bias0, b_res,
        gamma, beta, wvec, Pbuf, Hh, Th8A, Th8B,
        a_s0, a_d0, a_s1, a_d1, W1h, W2p, out, bar);
}

// Round 10
// 302.437 us; speedup vs baseline: 2.0905x; 2.0905x over previous
//
#include <hip/hip_runtime.h>
#include <hip/hip_fp8.h>
#include <math.h>

#define NND   32768
#define HIDD  128
#define NHEAD 64
#define BSS   512
#define OUTC  3

typedef _Float16 half_t;
typedef __attribute__((ext_vector_type(8))) _Float16 half8;  // MFMA A/B frag
typedef __attribute__((ext_vector_type(4))) float f32x4;     // MFMA C/D frag

__device__ __forceinline__ unsigned enc_fp8x4(float a, float b, float c, float d) {
    __hip_fp8x4_e4m3 q(make_float4(a, b, c, d));
    return (unsigned)q.__x;
}
__device__ __forceinline__ float4 dec_fp8x4(unsigned v) {
    __hip_fp8x4_e4m3 t; t.__x = (__hip_fp8x4_storage_t)v;
    return (float4)t;
}

// ---------------- prep: weight transposes, w_s/w_d GEMVs, x cast, edge count ----------
__global__ __launch_bounds__(256) void prep_kernel(const float* __restrict__ W0,
        const float* __restrict__ W_res, const float* __restrict__ W1p,
        const float* __restrict__ as0, const float* __restrict__ ad0,
        const float* __restrict__ as_res, const float* __restrict__ ad_res,
        const float* __restrict__ x, const int* __restrict__ ei, int E,
        half_t* __restrict__ Wh, half_t* __restrict__ W1h, half_t* __restrict__ W0t,
        float* __restrict__ wvec, half_t* __restrict__ xh,
        int* __restrict__ counts, int* __restrict__ rank) {
    int b = blockIdx.x, tid = threadIdx.x;
    if (b < 64) {            // W_res[l][128k][128n] -> Wh[l][n][k] fp16
        __shared__ float tile[32][33];
        int l = b >> 4, t = b & 15;
        int k0 = (t >> 2) * 32, n0 = (t & 3) * 32;
        const float* src = W_res + (size_t)l * 128 * 128;
        half_t* dst = Wh + (size_t)l * 128 * 128;
        int c = tid & 31, r0 = tid >> 5;
#pragma unroll
        for (int i = 0; i < 4; ++i) tile[r0 + i * 8][c] = src[(size_t)(k0 + r0 + i * 8) * 128 + n0 + c];
        __syncthreads();
#pragma unroll
        for (int i = 0; i < 4; ++i) dst[(size_t)(n0 + r0 + i * 8) * 128 + k0 + c] = (half_t)tile[c][r0 + i * 8];
    } else if (b < 576) {    // W1p[h][128k][64n] -> W1h[h][n][k] fp16
        __shared__ float tile[32][33];
        int bb = b - 64, head = bb >> 3, t = bb & 7;
        int k0 = (t >> 1) * 32, n0 = (t & 1) * 32;
        const float* src = W1p + (size_t)head * 128 * 64;
        half_t* dst = W1h + (size_t)head * 64 * 128;
        int c = tid & 31, r0 = tid >> 5;
#pragma unroll
        for (int i = 0; i < 4; ++i) tile[r0 + i * 8][c] = src[(size_t)(k0 + r0 + i * 8) * 64 + n0 + c];
        __syncthreads();
#pragma unroll
        for (int i = 0; i < 4; ++i) dst[(size_t)(n0 + r0 + i * 8) * 128 + k0 + c] = (half_t)tile[c][r0 + i * 8];
    } else if (b == 576) {   // W0[32k][128n] -> W0t[n][k] fp16
        __shared__ float t0[32][129];
        for (int i = tid; i < 4096; i += 256) t0[i >> 7][i & 127] = W0[i];
        __syncthreads();
        for (int i = tid; i < 4096; i += 256) { int n = i >> 5, k = i & 31; W0t[n * 32 + k] = (half_t)t0[k][n]; }
    } else if (b == 577) {   // w_s[l][k] = sum_n W_l[k][n]*att_src_l[n]; w_d at wvec+640
        for (int task = tid; task < 1088; task += 256) {
            const float* row; const float* att; int slot, sd;
            if (task < 64) {
                int k = task >> 1; sd = task & 1;
                row = W0 + k * 128; att = sd ? ad0 : as0; slot = k;
            } else {
                int tt = task - 64; int l = 1 + tt / 256; int r = tt % 256;
                int k = r >> 1; sd = r & 1;
                row = W_res + (size_t)(l - 1) * 16384 + k * 128;
                att = (sd ? ad_res : as_res) + (l - 1) * 128;
                slot = l * 128 + k;
            }
            float s = 0.f;
            for (int n = 0; n < 128; ++n) s += row[n] * att[n];
            (sd ? wvec + 640 : wvec)[slot] = s;
        }
    } else if (b < 1090) {   // x fp32 -> xh fp16
        int b2 = b - 578;
        const float* xs = x + (size_t)b2 * 64 * 32;
        half_t* xd = xh + (size_t)b2 * 64 * 32;
        for (int i = tid; i < 1024; i += 256) {
            float2 v = ((const float2*)xs)[i];
            union { unsigned u; half_t h[2]; } cv;
            cv.h[0] = (half_t)v.x; cv.h[1] = (half_t)v.y;
            ((unsigned*)xd)[i] = cv.u;
        }
    } else {                 // edge count + rank (counts pre-zeroed by memset)
        int j = (b - 1090) * 256 + tid;
        int Etot = E + NND;
        if (j >= Etot) return;
        int dst = (j < E) ? ei[E + j] : (j - E);
        rank[j] = atomicAdd(&counts[dst], 1);
    }
}

__global__ __launch_bounds__(1024) void scan_kernel(const int* __restrict__ counts,
                                                    int* __restrict__ off) {
    __shared__ int sums[1024];
    int tid = threadIdx.x;
    int base = tid * 32;
    int tmp[32];
    int run = 0;
#pragma unroll
    for (int i = 0; i < 8; ++i) {
        int4 c4 = *(const int4*)&counts[base + i * 4];
        tmp[i*4+0] = run; run += c4.x;
        tmp[i*4+1] = run; run += c4.y;
        tmp[i*4+2] = run; run += c4.z;
        tmp[i*4+3] = run; run += c4.w;
    }
    sums[tid] = run;
    __syncthreads();
    for (int d = 1; d < 1024; d <<= 1) {
        int v = (tid >= d) ? sums[tid - d] : 0;
        __syncthreads();
        sums[tid] += v;
        __syncthreads();
    }
    int ebase = (tid == 0) ? 0 : sums[tid - 1];
#pragma unroll
    for (int i = 0; i < 32; ++i) off[base + i] = ebase + tmp[i];
    if (tid == 1023) off[NND] = sums[1023];
}

// ---------------- CSR fill + layer-0 attention scalars (merged) ----------------
__global__ __launch_bounds__(256) void fill_a0_kernel(const int* __restrict__ ei, int E, int egrid,
        const int* __restrict__ off, const int* __restrict__ rank, int* __restrict__ csr_src,
        const half_t* __restrict__ xh, const float* __restrict__ wvec,
        float* __restrict__ a_s, float* __restrict__ a_d) {
    int b = blockIdx.x, tid = threadIdx.x;
    if (b < egrid) {
        int j = b * 256 + tid;
        int Etot = E + NND;
        if (j >= Etot) return;
        int src, dst;
        if (j < E) { src = ei[j]; dst = ei[E + j]; }
        else       { src = j - E; dst = j - E; }
        csr_src[off[dst] + rank[j]] = src;
    } else {
        __shared__ float ws0[32], wd0[32];
        if (tid < 32) { ws0[tid] = wvec[tid]; wd0[tid] = wvec[640 + tid]; }
        __syncthreads();
        int g = (b - egrid) * 256 + tid;
        int node = g >> 2, part = g & 3;
        half8 xv = *(const half8*)&xh[(size_t)node * 32 + part * 8];
        float s = 0.f, d2 = 0.f;
#pragma unroll
        for (int j = 0; j < 8; ++j) { float f = (float)xv[j]; s += f * ws0[part * 8 + j]; d2 += f * wd0[part * 8 + j]; }
        s += __shfl_xor(s, 1); s += __shfl_xor(s, 2);
        d2 += __shfl_xor(d2, 1); d2 += __shfl_xor(d2, 2);
        if (part == 0) { a_s[node] = s; a_d[node] = d2; }
    }
}

// ---------------- layer-0 aggregation over xh (32ch, fp16) ----------------
__global__ __launch_bounds__(256) void agg0_kernel(const half_t* __restrict__ xh,
        const float* __restrict__ a_s, const float* __restrict__ a_dv,
        const int* __restrict__ csr_src, const int* __restrict__ off,
        half_t* __restrict__ P) {
    int d = (blockIdx.x * 256 + threadIdx.x) >> 6;
    int lane = threadIdx.x & 63;
    int q = lane >> 4, r15 = lane & 15;
    int beg = off[d], end = off[d + 1];
    float adv = a_dv[d];
    float pz = 0.f, a0 = 0.f, a1 = 0.f;
    for (int base = beg; base < end; base += 64) {
        int j = base + lane;
        int s = 0; float p = 0.f;
        if (j < end) {
            s = csr_src[j];
            float t = a_s[s] + adv;
            t = (t > 0.f) ? t : 0.2f * t;
            p = __expf(t);
        }
        pz += p;
        int cnt = end - base; if (cnt > 64) cnt = 64;
        int full = cnt & ~15;
        int k4 = 0;
        for (; k4 < full; k4 += 16) {
            int s0 = __shfl(s, k4 + q);      float p0 = __shfl(p, k4 + q);
            int s1 = __shfl(s, k4 + 4 + q);  float p1 = __shfl(p, k4 + 4 + q);
            int s2 = __shfl(s, k4 + 8 + q);  float p2 = __shfl(p, k4 + 8 + q);
            int s3 = __shfl(s, k4 + 12 + q); float p3 = __shfl(p, k4 + 12 + q);
            union { unsigned u; half_t h[2]; } u0, u1, u2, u3;
            u0.u = *(const unsigned*)&xh[(size_t)s0 * 32 + r15 * 2];
            u1.u = *(const unsigned*)&xh[(size_t)s1 * 32 + r15 * 2];
            u2.u = *(const unsigned*)&xh[(size_t)s2 * 32 + r15 * 2];
            u3.u = *(const unsigned*)&xh[(size_t)s3 * 32 + r15 * 2];
            a0 += p0 * (float)u0.h[0] + p1 * (float)u1.h[0] + p2 * (float)u2.h[0] + p3 * (float)u3.h[0];
            a1 += p0 * (float)u0.h[1] + p1 * (float)u1.h[1] + p2 * (float)u2.h[1] + p3 * (float)u3.h[1];
        }
        for (; k4 < cnt; k4 += 4) {
            int s0 = __shfl(s, k4 + q); float p0 = __shfl(p, k4 + q);
            union { unsigned u; half_t h[2]; } u0;
            u0.u = *(const unsigned*)&xh[(size_t)s0 * 32 + r15 * 2];
            a0 += p0 * (float)u0.h[0]; a1 += p0 * (float)u0.h[1];
        }
    }
#pragma unroll
    for (int o = 32; o; o >>= 1) pz += __shfl_xor(pz, o);
    a0 += __shfl_xor(a0, 16); a0 += __shfl_xor(a0, 32);
    a1 += __shfl_xor(a1, 16); a1 += __shfl_xor(a1, 32);
    if (q == 0) {
        float inv = 1.f / (pz + 1e-16f);
        union { unsigned u; half_t h[2]; } w;
        w.h[0] = (half_t)(a0 * inv); w.h[1] = (half_t)(a1 * inv);
        *(unsigned*)&P[(size_t)d * 32 + r15 * 2] = w.u;
    }
}

// ---------------- res-layer aggregation over Th8 (128ch, fp8 e4m3) -------------------
// 32-edge staging blocks: 8 independent row-gathers in flight per lane (MLP 2x vs 16-edge)
__global__ __launch_bounds__(256) void agg_kernel(const unsigned char* __restrict__ F8,
        const float* __restrict__ a_s, const float* __restrict__ a_dv,
        const int* __restrict__ csr_src, const int* __restrict__ off,
        half_t* __restrict__ P) {
    int d = (blockIdx.x * 256 + threadIdx.x) >> 6;
    int lane = threadIdx.x & 63;
    int q = lane >> 4, r15 = lane & 15;
    int beg = off[d], end = off[d + 1];
    float adv = a_dv[d];
    float pz = 0.f;
    float acc[8] = {0.f,0.f,0.f,0.f,0.f,0.f,0.f,0.f};
    for (int base = beg; base < end; base += 64) {
        int j = base + lane;
        int s = 0; float p = 0.f;
        if (j < end) {
            s = csr_src[j];
            float t = a_s[s] + adv;
            t = (t > 0.f) ? t : 0.2f * t;
            p = __expf(t);
        }
        pz += p;
        int cnt = end - base; if (cnt > 64) cnt = 64;
        int full32 = cnt & ~31;
        int k4 = 0;
        for (; k4 < full32; k4 += 32) {   // 8 gathers in flight
            int   si[8]; float pi[8]; uint2 ri[8];
#pragma unroll
            for (int e = 0; e < 8; ++e) {
                si[e] = __shfl(s, k4 + e * 4 + q);
                pi[e] = __shfl(p, k4 + e * 4 + q);
            }
#pragma unroll
            for (int e = 0; e < 8; ++e)
                ri[e] = *(const uint2*)&F8[(size_t)si[e] * HIDD + r15 * 8];
#pragma unroll
            for (int e = 0; e < 8; ++e) {
                float4 f;
                f = dec_fp8x4(ri[e].x); acc[0]+=pi[e]*f.x; acc[1]+=pi[e]*f.y; acc[2]+=pi[e]*f.z; acc[3]+=pi[e]*f.w;
                f = dec_fp8x4(ri[e].y); acc[4]+=pi[e]*f.x; acc[5]+=pi[e]*f.y; acc[6]+=pi[e]*f.z; acc[7]+=pi[e]*f.w;
            }
        }
        int full16 = cnt & ~15;
        for (; k4 < full16; k4 += 16) {
            int s0 = __shfl(s, k4 + q);      float p0 = __shfl(p, k4 + q);
            int s1 = __shfl(s, k4 + 4 + q);  float p1 = __shfl(p, k4 + 4 + q);
            int s2 = __shfl(s, k4 + 8 + q);  float p2 = __shfl(p, k4 + 8 + q);
            int s3 = __shfl(s, k4 + 12 + q); float p3 = __shfl(p, k4 + 12 + q);
            uint2 r0 = *(const uint2*)&F8[(size_t)s0 * HIDD + r15 * 8];
            uint2 r1 = *(const uint2*)&F8[(size_t)s1 * HIDD + r15 * 8];
            uint2 r2 = *(const uint2*)&F8[(size_t)s2 * HIDD + r15 * 8];
            uint2 r3 = *(const uint2*)&F8[(size_t)s3 * HIDD + r15 * 8];
            float4 f;
            f = dec_fp8x4(r0.x); acc[0]+=p0*f.x; acc[1]+=p0*f.y; acc[2]+=p0*f.z; acc[3]+=p0*f.w;
            f = dec_fp8x4(r0.y); acc[4]+=p0*f.x; acc[5]+=p0*f.y; acc[6]+=p0*f.z; acc[7]+=p0*f.w;
            f = dec_fp8x4(r1.x); acc[0]+=p1*f.x; acc[1]+=p1*f.y; acc[2]+=p1*f.z; acc[3]+=p1*f.w;
            f = dec_fp8x4(r1.y); acc[4]+=p1*f.x; acc[5]+=p1*f.y; acc[6]+=p1*f.z; acc[7]+=p1*f.w;
            f = dec_fp8x4(r2.x); acc[0]+=p2*f.x; acc[1]+=p2*f.y; acc[2]+=p2*f.z; acc[3]+=p2*f.w;
            f = dec_fp8x4(r2.y); acc[4]+=p2*f.x; acc[5]+=p2*f.y; acc[6]+=p2*f.z; acc[7]+=p2*f.w;
            f = dec_fp8x4(r3.x); acc[0]+=p3*f.x; acc[1]+=p3*f.y; acc[2]+=p3*f.z; acc[3]+=p3*f.w;
            f = dec_fp8x4(r3.y); acc[4]+=p3*f.x; acc[5]+=p3*f.y; acc[6]+=p3*f.z; acc[7]+=p3*f.w;
        }
        for (; k4 < cnt; k4 += 4) {
            int s0 = __shfl(s, k4 + q); float p0 = __shfl(p, k4 + q);
            uint2 r0 = *(const uint2*)&F8[(size_t)s0 * HIDD + r15 * 8];
            float4 f;
            f = dec_fp8x4(r0.x); acc[0]+=p0*f.x; acc[1]+=p0*f.y; acc[2]+=p0*f.z; acc[3]+=p0*f.w;
            f = dec_fp8x4(r0.y); acc[4]+=p0*f.x; acc[5]+=p0*f.y; acc[6]+=p0*f.z; acc[7]+=p0*f.w;
        }
    }
#pragma unroll
    for (int o = 32; o; o >>= 1) pz += __shfl_xor(pz, o);
#pragma unroll
    for (int i = 0; i < 8; ++i) {
        acc[i] += __shfl_xor(acc[i], 16);
        acc[i] += __shfl_xor(acc[i], 32);
    }
    if (q == 0) {
        float inv = 1.f / (pz + 1e-16f);
        union { int4 v; half_t hh[8]; } u;
#pragma unroll
        for (int i = 0; i < 8; ++i) u.hh[i] = (half_t)(acc[i] * inv);
        *(int4*)&P[(size_t)d * HIDD + r15 * 8] = u.v;
    }
}

// ---------------- GEMM + coalesced fused epilogue (bias, residual fp16, LN, Th8, a_s/a_d) ----
template <int K, bool RES>
__global__ __launch_bounds__(256) void gemm_kernel(const half_t* __restrict__ P,
        const half_t* __restrict__ Whl, const float* __restrict__ bias,
        half_t* __restrict__ Hh, unsigned char* __restrict__ Th8,
        const float* __restrict__ gamma, const float* __restrict__ beta,
        const float* __restrict__ wsn, const float* __restrict__ wdn,
        float* __restrict__ a_s, float* __restrict__ a_d) {
    constexpr int KP = K + 8;
    constexpr int WB = 128 * KP * 2;
    constexpr int VB = 64 * 132 * 4;
    __shared__ __align__(16) char smraw[(WB > VB) ? WB : VB];
    half_t* w = (half_t*)smraw;
    float* vv = (float*)smraw;
    int tid = threadIdx.x;
    int n0 = blockIdx.x * 64;
    for (int i = tid; i < 128 * (K / 8); i += 256) {
        int n = i / (K / 8), c = i % (K / 8);
        *(int4*)&w[n * KP + c * 8] = *(const int4*)&Whl[(size_t)n * K + c * 8];
    }
    int wv = tid >> 6, lane = tid & 63;
    int q = lane >> 4, r15 = lane & 15;
    half8 afrag[K / 32];
    int nodeA = n0 + wv * 16 + r15;
#pragma unroll
    for (int s = 0; s < K / 32; ++s)
        afrag[s] = *(const half8*)&P[(size_t)nodeA * K + s * 32 + q * 8];
    __syncthreads();
    f32x4 acc[8];
#pragma unroll
    for (int ct = 0; ct < 8; ++ct) {
        f32x4 c = {0.f, 0.f, 0.f, 0.f};
#pragma unroll
        for (int s = 0; s < K / 32; ++s) {
            half8 bfrag = *(const half8*)&w[(ct * 16 + r15) * KP + s * 32 + q * 8];
            c = __builtin_amdgcn_mfma_f32_16x16x32_f16(afrag[s], bfrag, c, 0, 0, 0);
        }
        acc[ct] = c;
    }
    __syncthreads();   // done with w
#pragma unroll
    for (int ct = 0; ct < 8; ++ct)
#pragma unroll
        for (int r = 0; r < 4; ++r)
            vv[(wv * 16 + q * 4 + r) * 132 + ct * 16 + r15] = acc[ct][r];
    __syncthreads();
    // phase 2: group of 16 lanes per node, 8 ch per lane, 4 passes
    int grp = tid >> 4, sub = tid & 15;
    float4 bi0 = *(const float4*)&bias[sub * 8],  bi1 = *(const float4*)&bias[sub * 8 + 4];
    float4 g0  = *(const float4*)&gamma[sub * 8], g1  = *(const float4*)&gamma[sub * 8 + 4];
    float4 be0 = *(const float4*)&beta[sub * 8],  be1 = *(const float4*)&beta[sub * 8 + 4];
    float4 ws0 = *(const float4*)&wsn[sub * 8],   ws1 = *(const float4*)&wsn[sub * 8 + 4];
    float4 wd0 = *(const float4*)&wdn[sub * 8],   wd1 = *(const float4*)&wdn[sub * 8 + 4];
    float bi[8] = {bi0.x,bi0.y,bi0.z,bi0.w,bi1.x,bi1.y,bi1.z,bi1.w};
    float gg[8] = {g0.x,g0.y,g0.z,g0.w,g1.x,g1.y,g1.z,g1.w};
    float be[8] = {be0.x,be0.y,be0.z,be0.w,be1.x,be1.y,be1.z,be1.w};
    float ws[8] = {ws0.x,ws0.y,ws0.z,ws0.w,ws1.x,ws1.y,ws1.z,ws1.w};
    float wd[8] = {wd0.x,wd0.y,wd0.z,wd0.w,wd1.x,wd1.y,wd1.z,wd1.w};
#pragma unroll
    for (int pp = 0; pp < 4; ++pp) {
        int nl = grp + pp * 16;
        int node = n0 + nl;
        float v8[8];
#pragma unroll
        for (int j = 0; j < 8; ++j) v8[j] = vv[nl * 132 + sub * 8 + j] + bi[j];
        if (RES) {
            half8 hold = *(const half8*)&Hh[(size_t)node * HIDD + sub * 8];
#pragma unroll
            for (int j = 0; j < 8; ++j) v8[j] += (float)hold[j];
        } else {
#pragma unroll
            for (int j = 0; j < 8; ++j) v8[j] = fmaxf(v8[j], 0.f);
        }
        union { int4 i4; half_t h[8]; } hw;
#pragma unroll
        for (int j = 0; j < 8; ++j) hw.h[j] = (half_t)v8[j];
        *(int4*)&Hh[(size_t)node * HIDD + sub * 8] = hw.i4;
        // LN over the 16-lane group
        float sum = 0.f;
#pragma unroll
        for (int j = 0; j < 8; ++j) sum += v8[j];
#pragma unroll
        for (int o = 8; o; o >>= 1) sum += __shfl_xor(sum, o);
        float mu = sum * (1.f / HIDD);
        float var = 0.f;
#pragma unroll
        for (int j = 0; j < 8; ++j) { float dx = v8[j] - mu; var += dx * dx; }
#pragma unroll
        for (int o = 8; o; o >>= 1) var += __shfl_xor(var, o);
        float rs = rsqrtf(var * (1.f / HIDD) + 1e-5f);
        float tt[8];
        float asn = 0.f, adn = 0.f;
#pragma unroll
        for (int j = 0; j < 8; ++j) {
            float t = fmaxf((v8[j] - mu) * rs * gg[j] + be[j], 0.f);
            tt[j] = t;
            asn += t * ws[j];
            adn += t * wd[j];
        }
        uint2 tw;
        tw.x = enc_fp8x4(tt[0], tt[1], tt[2], tt[3]);
        tw.y = enc_fp8x4(tt[4], tt[5], tt[6], tt[7]);
        *(uint2*)&Th8[(size_t)node * HIDD + sub * 8] = tw;
#pragma unroll
        for (int o = 8; o; o >>= 1) { asn += __shfl_xor(asn, o); adn += __shfl_xor(adn, o); }
        if (sub == 0) { a_s[node] = asn; a_d[node] = adn; }
    }
}

// ---------------- last layer: GEMM + residual + LN + predictor head + softmax ----------
__global__ __launch_bounds__(256) void gemm_last_kernel(const half_t* __restrict__ P,
        const half_t* __restrict__ Whl, const float* __restrict__ bias,
        const half_t* __restrict__ Hh,
        const float* __restrict__ gamma, const float* __restrict__ beta,
        const half_t* __restrict__ W1h, const float* __restrict__ W2p,
        float* __restrict__ out) {
    __shared__ __align__(16) char smraw[128 * 136 * 2];
    half_t* w = (half_t*)smraw;
    float* vv = (float*)smraw;
    int tid = threadIdx.x;
    int n0 = blockIdx.x * 64;
    for (int i = tid; i < 128 * 16; i += 256) {
        int n = i >> 4, c = i & 15;
        *(int4*)&w[n * 136 + c * 8] = *(const int4*)&Whl[(size_t)n * 128 + c * 8];
    }
    int wv = tid >> 6, lane = tid & 63;
    int q = lane >> 4, r15 = lane & 15;
    half8 afrag[4];
    int nodeA = n0 + wv * 16 + r15;
#pragma unroll
    for (int s = 0; s < 4; ++s)
        afrag[s] = *(const half8*)&P[(size_t)nodeA * HIDD + s * 32 + q * 8];
    __syncthreads();
    f32x4 acc[8];
#pragma unroll
    for (int ct = 0; ct < 8; ++ct) {
        f32x4 c = {0.f, 0.f, 0.f, 0.f};
#pragma unroll
        for (int s = 0; s < 4; ++s) {
            half8 bfrag = *(const half8*)&w[(ct * 16 + r15) * 136 + s * 32 + q * 8];
            c = __builtin_amdgcn_mfma_f32_16x16x32_f16(afrag[s], bfrag, c, 0, 0, 0);
        }
        acc[ct] = c;
    }
    __syncthreads();
#pragma unroll
    for (int ct = 0; ct < 8; ++ct)
#pragma unroll
        for (int r = 0; r < 4; ++r)
            vv[(wv * 16 + q * 4 + r) * 132 + ct * 16 + r15] = acc[ct][r];
    __syncthreads();
    int grp = tid >> 4, sub = tid & 15;
    float4 bi0 = *(const float4*)&bias[sub * 8],  bi1 = *(const float4*)&bias[sub * 8 + 4];
    float4 g0  = *(const float4*)&gamma[sub * 8], g1  = *(const float4*)&gamma[sub * 8 + 4];
    float4 be0 = *(const float4*)&beta[sub * 8],  be1 = *(const float4*)&beta[sub * 8 + 4];
    float bi[8] = {bi0.x,bi0.y,bi0.z,bi0.w,bi1.x,bi1.y,bi1.z,bi1.w};
    float gg[8] = {g0.x,g0.y,g0.z,g0.w,g1.x,g1.y,g1.z,g1.w};
    float be[8] = {be0.x,be0.y,be0.z,be0.w,be1.x,be1.y,be1.z,be1.w};
    half_t tv[4][8];
#pragma unroll
    for (int pp = 0; pp < 4; ++pp) {
        int nl = grp + pp * 16;
        int node = n0 + nl;
        float v8[8];
        half8 hold = *(const half8*)&Hh[(size_t)node * HIDD + sub * 8];
#pragma unroll
        for (int j = 0; j < 8; ++j) v8[j] = vv[nl * 132 + sub * 8 + j] + bi[j] + (float)hold[j];
        float sum = 0.f;
#pragma unroll
        for (int j = 0; j < 8; ++j) sum += v8[j];
#pragma unroll
        for (int o = 8; o; o >>= 1) sum += __shfl_xor(sum, o);
        float mu = sum * (1.f / HIDD);
        float var = 0.f;
#pragma unroll
        for (int j = 0; j < 8; ++j) { float dx = v8[j] - mu; var += dx * dx; }
#pragma unroll
        for (int o = 8; o; o >>= 1) var += __shfl_xor(var, o);
        float rs = rsqrtf(var * (1.f / HIDD) + 1e-5f);
#pragma unroll
        for (int j = 0; j < 8; ++j)
            tv[pp][j] = (half_t)fmaxf((v8[j] - mu) * rs * gg[j] + be[j], 0.f);
    }
    __syncthreads();   // done reading vv; rewrite w region with T tile (136-pad half rows)
#pragma unroll
    for (int pp = 0; pp < 4; ++pp) {
        int nl = grp + pp * 16;
        union { int4 i4; half_t h[8]; } u;
#pragma unroll
        for (int j = 0; j < 8; ++j) u.h[j] = tv[pp][j];
        *(int4*)&w[nl * 136 + sub * 8] = u.i4;
    }
    __syncthreads();
    // predictor head (nodes of this block all belong to head n0>>9)
    int head = n0 >> 9;
    const half_t* W1g = W1h + (size_t)head * 64 * 128;
    half8 pa[4];
#pragma unroll
    for (int s = 0; s < 4; ++s)
        pa[s] = *(const half8*)&w[(wv * 16 + r15) * 136 + s * 32 + q * 8];
    float lg[3][4];
#pragma unroll
    for (int o = 0; o < 3; ++o)
#pragma unroll
        for (int r = 0; r < 4; ++r) lg[o][r] = 0.f;
#pragma unroll
    for (int ct2 = 0; ct2 < 4; ++ct2) {
        int n2 = ct2 * 16 + r15;
        f32x4 c = {0.f, 0.f, 0.f, 0.f};
#pragma unroll
        for (int s = 0; s < 4; ++s) {
            half8 bfrag = *(const half8*)&W1g[(size_t)n2 * 128 + s * 32 + q * 8];
            c = __builtin_amdgcn_mfma_f32_16x16x32_f16(pa[s], bfrag, c, 0, 0, 0);
        }
        float w2a = W2p[(size_t)head * 192 + n2 * 3 + 0];
        float w2b = W2p[(size_t)head * 192 + n2 * 3 + 1];
        float w2c = W2p[(size_t)head * 192 + n2 * 3 + 2];
#pragma unroll
        for (int r = 0; r < 4; ++r) {
            float t = fmaxf(c[r], 0.f);
            lg[0][r] += t * w2a;
            lg[1][r] += t * w2b;
            lg[2][r] += t * w2c;
        }
    }
#pragma unroll
    for (int o = 8; o; o >>= 1)
#pragma unroll
        for (int oo = 0; oo < 3; ++oo)
#pragma unroll
            for (int r = 0; r < 4; ++r) lg[oo][r] += __shfl_xor(lg[oo][r], o);
    if (r15 == 0) {
        int nodeD = n0 + wv * 16 + q * 4;
#pragma unroll
        for (int r = 0; r < 4; ++r) {
            float l0 = lg[0][r], l1 = lg[1][r], l2 = lg[2][r];
            float mx = fmaxf(l0, fmaxf(l1, l2));
            float e0 = __expf(l0 - mx), e1 = __expf(l1 - mx), e2 = __expf(l2 - mx);
            float inv = 1.f / (e0 + e1 + e2);
            float* op = out + (size_t)(nodeD + r) * OUTC;
            op[0] = e0 * inv; op[1] = e1 * inv; op[2] = e2 * inv;
        }
    }
}

extern "C" void kernel_launch(void* const* d_in, const int* in_sizes, int n_in,
                              void* d_out, int out_size, void* d_ws, size_t ws_size,
                              hipStream_t stream) {
    const float* x        = (const float*)d_in[0];
    const int*   ei       = (const int*)d_in[1];
    const float* W0       = (const float*)d_in[2];
    const float* att_src0 = (const float*)d_in[3];
    const float* att_dst0 = (const float*)d_in[4];
    const float* bias0    = (const float*)d_in[5];
    const float* W_res    = (const float*)d_in[6];
    const float* as_res   = (const float*)d_in[7];
    const float* ad_res   = (const float*)d_in[8];
    const float* b_res    = (const float*)d_in[9];
    const float* gamma    = (const float*)d_in[10];
    const float* beta     = (const float*)d_in[11];
    const float* W1p      = (const float*)d_in[12];
    const float* W2p      = (const float*)d_in[13];
    float* out = (float*)d_out;

    int E = in_sizes[1] / 2;
    int Etot = E + NND;

    char* p = (char*)d_ws;
    auto alloc = [&](size_t bytes) { void* r = (void*)p; p += (bytes + 255) & ~(size_t)255; return r; };
    int*    counts  = (int*)alloc((size_t)NND * 4);
    int*    off     = (int*)alloc((size_t)(NND + 1) * 4);
    int*    rank    = (int*)alloc((size_t)Etot * 4);
    int*    csr_src = (int*)alloc((size_t)Etot * 4);
    half_t* xh      = (half_t*)alloc((size_t)NND * 32 * 2);
    half_t* Pbuf    = (half_t*)alloc((size_t)NND * HIDD * 2);
    unsigned char* Th8 = (unsigned char*)alloc((size_t)NND * HIDD);
    half_t* Hh      = (half_t*)alloc((size_t)NND * HIDD * 2);
    float*  a_s     = (float*)alloc((size_t)NND * 4);
    float*  a_d     = (float*)alloc((size_t)NND * 4);
    half_t* Wh      = (half_t*)alloc((size_t)4 * HIDD * HIDD * 2);
    half_t* W1h     = (half_t*)alloc((size_t)NHEAD * 64 * HIDD * 2);
    half_t* W0t     = (half_t*)alloc((size_t)HIDD * 32 * 2);
    float*  wvec    = (float*)alloc((size_t)1280 * 4);

    int egrid = (Etot + 255) / 256;

    hipMemsetAsync(counts, 0, (size_t)NND * 4, stream);
    prep_kernel<<<1090 + egrid, 256, 0, stream>>>(W0, W_res, W1p, att_src0, att_dst0,
        as_res, ad_res, x, ei, E, Wh, W1h, W0t, wvec, xh, counts, rank);
    scan_kernel<<<1, 1024, 0, stream>>>(counts, off);
    fill_a0_kernel<<<egrid + 512, 256, 0, stream>>>(ei, E, egrid, off, rank, csr_src,
                                                    xh, wvec, a_s, a_d);

    // layer 0
    agg0_kernel<<<NND / 4, 256, 0, stream>>>(xh, a_s, a_d, csr_src, off, Pbuf);
    gemm_kernel<32, false><<<NND / 64, 256, 0, stream>>>(Pbuf, W0t, bias0, Hh, Th8,
        gamma, beta, wvec + 128, wvec + 640 + 128, a_s, a_d);

    // res blocks 0..2
    for (int i = 0; i < 3; ++i) {
        agg_kernel<<<NND / 4, 256, 0, stream>>>(Th8, a_s, a_d, csr_src, off, Pbuf);
        gemm_kernel<128, true><<<NND / 64, 256, 0, stream>>>(Pbuf, Wh + (size_t)i * 16384,
            b_res + i * HIDD, Hh, Th8,
            gamma + (i + 1) * HIDD, beta + (i + 1) * HIDD,
            wvec + (i + 2) * 128, wvec + 640 + (i + 2) * 128, a_s, a_d);
    }

    // res block 3 + final LN + predictor + softmax
    agg_kernel<<<NND / 4, 256, 0, stream>>>(Th8, a_s, a_d, csr_src, off, Pbuf);
    gemm_last_kernel<<<NND / 64, 256, 0, stream>>>(Pbuf, Wh + (size_t)3 * 16384,
        b_res + 3 * HIDD, Hh, gamma, beta, W1h, W2p, out);
}

// Round 11
// 281.280 us; speedup vs baseline: 2.2477x; 1.0752x over previous
//
#include <hip/hip_runtime.h>
#include <hip/hip_fp8.h>
#include <math.h>

#define NND   32768
#define HIDD  128
#define NHEAD 64
#define BSS   512
#define OUTC  3

typedef _Float16 half_t;
typedef __attribute__((ext_vector_type(8))) _Float16 half8;  // MFMA A/B frag
typedef __attribute__((ext_vector_type(4))) float f32x4;     // MFMA C/D frag

__device__ __forceinline__ unsigned enc_fp8x4(float a, float b, float c, float d) {
    __hip_fp8x4_e4m3 q(make_float4(a, b, c, d));
    return (unsigned)q.__x;
}
__device__ __forceinline__ float4 dec_fp8x4(unsigned v) {
    __hip_fp8x4_e4m3 t; t.__x = (__hip_fp8x4_storage_t)v;
    return (float4)t;
}

// ---------------- prep: weight transposes, w_s/w_d GEMVs, x cast, edge count ----------
__global__ __launch_bounds__(256) void prep_kernel(const float* __restrict__ W0,
        const float* __restrict__ W_res, const float* __restrict__ W1p,
        const float* __restrict__ as0, const float* __restrict__ ad0,
        const float* __restrict__ as_res, const float* __restrict__ ad_res,
        const float* __restrict__ x, const int* __restrict__ ei, int E,
        half_t* __restrict__ Wh, half_t* __restrict__ W1h, half_t* __restrict__ W0t,
        float* __restrict__ wvec, half_t* __restrict__ xh,
        int* __restrict__ counts, int* __restrict__ rank) {
    int b = blockIdx.x, tid = threadIdx.x;
    if (b < 64) {            // W_res[l][128k][128n] -> Wh[l][n][k] fp16
        __shared__ float tile[32][33];
        int l = b >> 4, t = b & 15;
        int k0 = (t >> 2) * 32, n0 = (t & 3) * 32;
        const float* src = W_res + (size_t)l * 128 * 128;
        half_t* dst = Wh + (size_t)l * 128 * 128;
        int c = tid & 31, r0 = tid >> 5;
#pragma unroll
        for (int i = 0; i < 4; ++i) tile[r0 + i * 8][c] = src[(size_t)(k0 + r0 + i * 8) * 128 + n0 + c];
        __syncthreads();
#pragma unroll
        for (int i = 0; i < 4; ++i) dst[(size_t)(n0 + r0 + i * 8) * 128 + k0 + c] = (half_t)tile[c][r0 + i * 8];
    } else if (b < 576) {    // W1p[h][128k][64n] -> W1h[h][n][k] fp16
        __shared__ float tile[32][33];
        int bb = b - 64, head = bb >> 3, t = bb & 7;
        int k0 = (t >> 1) * 32, n0 = (t & 1) * 32;
        const float* src = W1p + (size_t)head * 128 * 64;
        half_t* dst = W1h + (size_t)head * 64 * 128;
        int c = tid & 31, r0 = tid >> 5;
#pragma unroll
        for (int i = 0; i < 4; ++i) tile[r0 + i * 8][c] = src[(size_t)(k0 + r0 + i * 8) * 64 + n0 + c];
        __syncthreads();
#pragma unroll
        for (int i = 0; i < 4; ++i) dst[(size_t)(n0 + r0 + i * 8) * 128 + k0 + c] = (half_t)tile[c][r0 + i * 8];
    } else if (b == 576) {   // W0[32k][128n] -> W0t[n][k] fp16
        __shared__ float t0[32][129];
        for (int i = tid; i < 4096; i += 256) t0[i >> 7][i & 127] = W0[i];
        __syncthreads();
        for (int i = tid; i < 4096; i += 256) { int n = i >> 5, k = i & 31; W0t[n * 32 + k] = (half_t)t0[k][n]; }
    } else if (b == 577) {   // w_s[l][k] = sum_n W_l[k][n]*att_src_l[n]; w_d at wvec+640
        for (int task = tid; task < 1088; task += 256) {
            const float* row; const float* att; int slot, sd;
            if (task < 64) {
                int k = task >> 1; sd = task & 1;
                row = W0 + k * 128; att = sd ? ad0 : as0; slot = k;
            } else {
                int tt = task - 64; int l = 1 + tt / 256; int r = tt % 256;
                int k = r >> 1; sd = r & 1;
                row = W_res + (size_t)(l - 1) * 16384 + k * 128;
                att = (sd ? ad_res : as_res) + (l - 1) * 128;
                slot = l * 128 + k;
            }
            float s = 0.f;
            for (int n = 0; n < 128; ++n) s += row[n] * att[n];
            (sd ? wvec + 640 : wvec)[slot] = s;
        }
    } else if (b < 1090) {   // x fp32 -> xh fp16
        int b2 = b - 578;
        const float* xs = x + (size_t)b2 * 64 * 32;
        half_t* xd = xh + (size_t)b2 * 64 * 32;
        for (int i = tid; i < 1024; i += 256) {
            float2 v = ((const float2*)xs)[i];
            union { unsigned u; half_t h[2]; } cv;
            cv.h[0] = (half_t)v.x; cv.h[1] = (half_t)v.y;
            ((unsigned*)xd)[i] = cv.u;
        }
    } else {                 // edge count + rank (counts pre-zeroed by memset)
        int j = (b - 1090) * 256 + tid;
        int Etot = E + NND;
        if (j >= Etot) return;
        int dst = (j < E) ? ei[E + j] : (j - E);
        rank[j] = atomicAdd(&counts[dst], 1);
    }
}

__global__ __launch_bounds__(1024) void scan_kernel(const int* __restrict__ counts,
                                                    int* __restrict__ off) {
    __shared__ int sums[1024];
    int tid = threadIdx.x;
    int base = tid * 32;
    int tmp[32];
    int run = 0;
#pragma unroll
    for (int i = 0; i < 8; ++i) {
        int4 c4 = *(const int4*)&counts[base + i * 4];
        tmp[i*4+0] = run; run += c4.x;
        tmp[i*4+1] = run; run += c4.y;
        tmp[i*4+2] = run; run += c4.z;
        tmp[i*4+3] = run; run += c4.w;
    }
    sums[tid] = run;
    __syncthreads();
    for (int d = 1; d < 1024; d <<= 1) {
        int v = (tid >= d) ? sums[tid - d] : 0;
        __syncthreads();
        sums[tid] += v;
        __syncthreads();
    }
    int ebase = (tid == 0) ? 0 : sums[tid - 1];
#pragma unroll
    for (int i = 0; i < 32; ++i) off[base + i] = ebase + tmp[i];
    if (tid == 1023) off[NND] = sums[1023];
}

// ---------------- CSR fill + layer-0 attention scalars (merged) ----------------
__global__ __launch_bounds__(256) void fill_a0_kernel(const int* __restrict__ ei, int E, int egrid,
        const int* __restrict__ off, const int* __restrict__ rank, int* __restrict__ csr_src,
        const half_t* __restrict__ xh, const float* __restrict__ wvec,
        float* __restrict__ a_s, float* __restrict__ a_d) {
    int b = blockIdx.x, tid = threadIdx.x;
    if (b < egrid) {
        int j = b * 256 + tid;
        int Etot = E + NND;
        if (j >= Etot) return;
        int src, dst;
        if (j < E) { src = ei[j]; dst = ei[E + j]; }
        else       { src = j - E; dst = j - E; }
        csr_src[off[dst] + rank[j]] = src;
    } else {
        __shared__ float ws0[32], wd0[32];
        if (tid < 32) { ws0[tid] = wvec[tid]; wd0[tid] = wvec[640 + tid]; }
        __syncthreads();
        int g = (b - egrid) * 256 + tid;
        int node = g >> 2, part = g & 3;
        half8 xv = *(const half8*)&xh[(size_t)node * 32 + part * 8];
        float s = 0.f, d2 = 0.f;
#pragma unroll
        for (int j = 0; j < 8; ++j) { float f = (float)xv[j]; s += f * ws0[part * 8 + j]; d2 += f * wd0[part * 8 + j]; }
        s += __shfl_xor(s, 1); s += __shfl_xor(s, 2);
        d2 += __shfl_xor(d2, 1); d2 += __shfl_xor(d2, 2);
        if (part == 0) { a_s[node] = s; a_d[node] = d2; }
    }
}

// ---------------- layer-0 aggregation over xh (32ch, fp16) ----------------
__global__ __launch_bounds__(256) void agg0_kernel(const half_t* __restrict__ xh,
        const float* __restrict__ a_s, const float* __restrict__ a_dv,
        const int* __restrict__ csr_src, const int* __restrict__ off,
        half_t* __restrict__ P) {
    int d = (blockIdx.x * 256 + threadIdx.x) >> 6;
    int lane = threadIdx.x & 63;
    int q = lane >> 4, r15 = lane & 15;
    int beg = off[d], end = off[d + 1];
    float adv = a_dv[d];
    float pz = 0.f, a0 = 0.f, a1 = 0.f;
    for (int base = beg; base < end; base += 64) {
        int j = base + lane;
        int s = 0; float p = 0.f;
        if (j < end) {
            s = csr_src[j];
            float t = a_s[s] + adv;
            t = (t > 0.f) ? t : 0.2f * t;
            p = __expf(t);
        }
        pz += p;
        int cnt = end - base; if (cnt > 64) cnt = 64;
        int full = cnt & ~15;
        int k4 = 0;
        for (; k4 < full; k4 += 16) {
            int s0 = __shfl(s, k4 + q);      float p0 = __shfl(p, k4 + q);
            int s1 = __shfl(s, k4 + 4 + q);  float p1 = __shfl(p, k4 + 4 + q);
            int s2 = __shfl(s, k4 + 8 + q);  float p2 = __shfl(p, k4 + 8 + q);
            int s3 = __shfl(s, k4 + 12 + q); float p3 = __shfl(p, k4 + 12 + q);
            union { unsigned u; half_t h[2]; } u0, u1, u2, u3;
            u0.u = *(const unsigned*)&xh[(size_t)s0 * 32 + r15 * 2];
            u1.u = *(const unsigned*)&xh[(size_t)s1 * 32 + r15 * 2];
            u2.u = *(const unsigned*)&xh[(size_t)s2 * 32 + r15 * 2];
            u3.u = *(const unsigned*)&xh[(size_t)s3 * 32 + r15 * 2];
            a0 += p0 * (float)u0.h[0] + p1 * (float)u1.h[0] + p2 * (float)u2.h[0] + p3 * (float)u3.h[0];
            a1 += p0 * (float)u0.h[1] + p1 * (float)u1.h[1] + p2 * (float)u2.h[1] + p3 * (float)u3.h[1];
        }
        for (; k4 < cnt; k4 += 4) {
            int s0 = __shfl(s, k4 + q); float p0 = __shfl(p, k4 + q);
            union { unsigned u; half_t h[2]; } u0;
            u0.u = *(const unsigned*)&xh[(size_t)s0 * 32 + r15 * 2];
            a0 += p0 * (float)u0.h[0]; a1 += p0 * (float)u0.h[1];
        }
    }
#pragma unroll
    for (int o = 32; o; o >>= 1) pz += __shfl_xor(pz, o);
    a0 += __shfl_xor(a0, 16); a0 += __shfl_xor(a0, 32);
    a1 += __shfl_xor(a1, 16); a1 += __shfl_xor(a1, 32);
    if (q == 0) {
        float inv = 1.f / (pz + 1e-16f);
        union { unsigned u; half_t h[2]; } w;
        w.h[0] = (half_t)(a0 * inv); w.h[1] = (half_t)(a1 * inv);
        *(unsigned*)&P[(size_t)d * 32 + r15 * 2] = w.u;
    }
}

// ---------------- res-layer aggregation over Th8 (128ch, fp8 e4m3, L2-resident) -------
__global__ __launch_bounds__(256) void agg_kernel(const unsigned char* __restrict__ F8,
        const float* __restrict__ a_s, const float* __restrict__ a_dv,
        const int* __restrict__ csr_src, const int* __restrict__ off,
        half_t* __restrict__ P) {
    int d = (blockIdx.x * 256 + threadIdx.x) >> 6;
    int lane = threadIdx.x & 63;
    int q = lane >> 4, r15 = lane & 15;
    int beg = off[d], end = off[d + 1];
    float adv = a_dv[d];
    float pz = 0.f;
    float acc[8] = {0.f,0.f,0.f,0.f,0.f,0.f,0.f,0.f};
    for (int base = beg; base < end; base += 64) {
        int j = base + lane;
        int s = 0; float p = 0.f;
        if (j < end) {
            s = csr_src[j];
            float t = a_s[s] + adv;
            t = (t > 0.f) ? t : 0.2f * t;
            p = __expf(t);
        }
        pz += p;
        int cnt = end - base; if (cnt > 64) cnt = 64;
        int full = cnt & ~15;
        int k4 = 0;
        for (; k4 < full; k4 += 16) {
            int s0 = __shfl(s, k4 + q);      float p0 = __shfl(p, k4 + q);
            int s1 = __shfl(s, k4 + 4 + q);  float p1 = __shfl(p, k4 + 4 + q);
            int s2 = __shfl(s, k4 + 8 + q);  float p2 = __shfl(p, k4 + 8 + q);
            int s3 = __shfl(s, k4 + 12 + q); float p3 = __shfl(p, k4 + 12 + q);
            uint2 r0 = *(const uint2*)&F8[(size_t)s0 * HIDD + r15 * 8];
            uint2 r1 = *(const uint2*)&F8[(size_t)s1 * HIDD + r15 * 8];
            uint2 r2 = *(const uint2*)&F8[(size_t)s2 * HIDD + r15 * 8];
            uint2 r3 = *(const uint2*)&F8[(size_t)s3 * HIDD + r15 * 8];
            float4 f;
            f = dec_fp8x4(r0.x); acc[0]+=p0*f.x; acc[1]+=p0*f.y; acc[2]+=p0*f.z; acc[3]+=p0*f.w;
            f = dec_fp8x4(r0.y); acc[4]+=p0*f.x; acc[5]+=p0*f.y; acc[6]+=p0*f.z; acc[7]+=p0*f.w;
            f = dec_fp8x4(r1.x); acc[0]+=p1*f.x; acc[1]+=p1*f.y; acc[2]+=p1*f.z; acc[3]+=p1*f.w;
            f = dec_fp8x4(r1.y); acc[4]+=p1*f.x; acc[5]+=p1*f.y; acc[6]+=p1*f.z; acc[7]+=p1*f.w;
            f = dec_fp8x4(r2.x); acc[0]+=p2*f.x; acc[1]+=p2*f.y; acc[2]+=p2*f.z; acc[3]+=p2*f.w;
            f = dec_fp8x4(r2.y); acc[4]+=p2*f.x; acc[5]+=p2*f.y; acc[6]+=p2*f.z; acc[7]+=p2*f.w;
            f = dec_fp8x4(r3.x); acc[0]+=p3*f.x; acc[1]+=p3*f.y; acc[2]+=p3*f.z; acc[3]+=p3*f.w;
            f = dec_fp8x4(r3.y); acc[4]+=p3*f.x; acc[5]+=p3*f.y; acc[6]+=p3*f.z; acc[7]+=p3*f.w;
        }
        for (; k4 < cnt; k4 += 4) {
            int s0 = __shfl(s, k4 + q); float p0 = __shfl(p, k4 + q);
            uint2 r0 = *(const uint2*)&F8[(size_t)s0 * HIDD + r15 * 8];
            float4 f;
            f = dec_fp8x4(r0.x); acc[0]+=p0*f.x; acc[1]+=p0*f.y; acc[2]+=p0*f.z; acc[3]+=p0*f.w;
            f = dec_fp8x4(r0.y); acc[4]+=p0*f.x; acc[5]+=p0*f.y; acc[6]+=p0*f.z; acc[7]+=p0*f.w;
        }
    }
#pragma unroll
    for (int o = 32; o; o >>= 1) pz += __shfl_xor(pz, o);
#pragma unroll
    for (int i = 0; i < 8; ++i) {
        acc[i] += __shfl_xor(acc[i], 16);
        acc[i] += __shfl_xor(acc[i], 32);
    }
    if (q == 0) {
        float inv = 1.f / (pz + 1e-16f);
        union { int4 v; half_t hh[8]; } u;
#pragma unroll
        for (int i = 0; i < 8; ++i) u.hh[i] = (half_t)(acc[i] * inv);
        *(int4*)&P[(size_t)d * HIDD + r15 * 8] = u.v;
    }
}

// ---------------- GEMM + coalesced fused epilogue (bias, residual fp16, LN, Th8, a_s/a_d) ----
template <int K, bool RES>
__global__ __launch_bounds__(256) void gemm_kernel(const half_t* __restrict__ P,
        const half_t* __restrict__ Whl, const float* __restrict__ bias,
        half_t* __restrict__ Hh, unsigned char* __restrict__ Th8,
        const float* __restrict__ gamma, const float* __restrict__ beta,
        const float* __restrict__ wsn, const float* __restrict__ wdn,
        float* __restrict__ a_s, float* __restrict__ a_d) {
    constexpr int KP = K + 8;
    constexpr int WB = 128 * KP * 2;
    constexpr int VB = 64 * 132 * 4;
    __shared__ __align__(16) char smraw[(WB > VB) ? WB : VB];
    half_t* w = (half_t*)smraw;
    float* vv = (float*)smraw;
    int tid = threadIdx.x;
    int n0 = blockIdx.x * 64;
    for (int i = tid; i < 128 * (K / 8); i += 256) {
        int n = i / (K / 8), c = i % (K / 8);
        *(int4*)&w[n * KP + c * 8] = *(const int4*)&Whl[(size_t)n * K + c * 8];
    }
    int wv = tid >> 6, lane = tid & 63;
    int q = lane >> 4, r15 = lane & 15;
    half8 afrag[K / 32];
    int nodeA = n0 + wv * 16 + r15;
#pragma unroll
    for (int s = 0; s < K / 32; ++s)
        afrag[s] = *(const half8*)&P[(size_t)nodeA * K + s * 32 + q * 8];
    __syncthreads();
    f32x4 acc[8];
#pragma unroll
    for (int ct = 0; ct < 8; ++ct) {
        f32x4 c = {0.f, 0.f, 0.f, 0.f};
#pragma unroll
        for (int s = 0; s < K / 32; ++s) {
            half8 bfrag = *(const half8*)&w[(ct * 16 + r15) * KP + s * 32 + q * 8];
            c = __builtin_amdgcn_mfma_f32_16x16x32_f16(afrag[s], bfrag, c, 0, 0, 0);
        }
        acc[ct] = c;
    }
    __syncthreads();   // done with w
#pragma unroll
    for (int ct = 0; ct < 8; ++ct)
#pragma unroll
        for (int r = 0; r < 4; ++r)
            vv[(wv * 16 + q * 4 + r) * 132 + ct * 16 + r15] = acc[ct][r];
    __syncthreads();
    // phase 2: group of 16 lanes per node, 8 ch per lane, 4 passes
    int grp = tid >> 4, sub = tid & 15;
    float4 bi0 = *(const float4*)&bias[sub * 8],  bi1 = *(const float4*)&bias[sub * 8 + 4];
    float4 g0  = *(const float4*)&gamma[sub * 8], g1  = *(const float4*)&gamma[sub * 8 + 4];
    float4 be0 = *(const float4*)&beta[sub * 8],  be1 = *(const float4*)&beta[sub * 8 + 4];
    float4 ws0 = *(const float4*)&wsn[sub * 8],   ws1 = *(const float4*)&wsn[sub * 8 + 4];
    float4 wd0 = *(const float4*)&wdn[sub * 8],   wd1 = *(const float4*)&wdn[sub * 8 + 4];
    float bi[8] = {bi0.x,bi0.y,bi0.z,bi0.w,bi1.x,bi1.y,bi1.z,bi1.w};
    float gg[8] = {g0.x,g0.y,g0.z,g0.w,g1.x,g1.y,g1.z,g1.w};
    float be[8] = {be0.x,be0.y,be0.z,be0.w,be1.x,be1.y,be1.z,be1.w};
    float ws[8] = {ws0.x,ws0.y,ws0.z,ws0.w,ws1.x,ws1.y,ws1.z,ws1.w};
    float wd[8] = {wd0.x,wd0.y,wd0.z,wd0.w,wd1.x,wd1.y,wd1.z,wd1.w};
#pragma unroll
    for (int pp = 0; pp < 4; ++pp) {
        int nl = grp + pp * 16;
        int node = n0 + nl;
        float v8[8];
#pragma unroll
        for (int j = 0; j < 8; ++j) v8[j] = vv[nl * 132 + sub * 8 + j] + bi[j];
        if (RES) {
            half8 hold = *(const half8*)&Hh[(size_t)node * HIDD + sub * 8];
#pragma unroll
            for (int j = 0; j < 8; ++j) v8[j] += (float)hold[j];
        } else {
#pragma unroll
            for (int j = 0; j < 8; ++j) v8[j] = fmaxf(v8[j], 0.f);
        }
        union { int4 i4; half_t h[8]; } hw;
#pragma unroll
        for (int j = 0; j < 8; ++j) hw.h[j] = (half_t)v8[j];
        *(int4*)&Hh[(size_t)node * HIDD + sub * 8] = hw.i4;
        // LN over the 16-lane group
        float sum = 0.f;
#pragma unroll
        for (int j = 0; j < 8; ++j) sum += v8[j];
#pragma unroll
        for (int o = 8; o; o >>= 1) sum += __shfl_xor(sum, o);
        float mu = sum * (1.f / HIDD);
        float var = 0.f;
#pragma unroll
        for (int j = 0; j < 8; ++j) { float dx = v8[j] - mu; var += dx * dx; }
#pragma unroll
        for (int o = 8; o; o >>= 1) var += __shfl_xor(var, o);
        float rs = rsqrtf(var * (1.f / HIDD) + 1e-5f);
        float tt[8];
        float asn = 0.f, adn = 0.f;
#pragma unroll
        for (int j = 0; j < 8; ++j) {
            float t = fmaxf((v8[j] - mu) * rs * gg[j] + be[j], 0.f);
            tt[j] = t;
            asn += t * ws[j];
            adn += t * wd[j];
        }
        uint2 tw;
        tw.x = enc_fp8x4(tt[0], tt[1], tt[2], tt[3]);
        tw.y = enc_fp8x4(tt[4], tt[5], tt[6], tt[7]);
        *(uint2*)&Th8[(size_t)node * HIDD + sub * 8] = tw;
#pragma unroll
        for (int o = 8; o; o >>= 1) { asn += __shfl_xor(asn, o); adn += __shfl_xor(adn, o); }
        if (sub == 0) { a_s[node] = asn; a_d[node] = adn; }
    }
}

// ---------------- last layer: GEMM + residual + LN + predictor head + softmax ----------
__global__ __launch_bounds__(256) void gemm_last_kernel(const half_t* __restrict__ P,
        const half_t* __restrict__ Whl, const float* __restrict__ bias,
        const half_t* __restrict__ Hh,
        const float* __restrict__ gamma, const float* __restrict__ beta,
        const half_t* __restrict__ W1h, const float* __restrict__ W2p,
        float* __restrict__ out) {
    __shared__ __align__(16) char smraw[128 * 136 * 2];
    half_t* w = (half_t*)smraw;
    float* vv = (float*)smraw;
    int tid = threadIdx.x;
    int n0 = blockIdx.x * 64;
    for (int i = tid; i < 128 * 16; i += 256) {
        int n = i >> 4, c = i & 15;
        *(int4*)&w[n * 136 + c * 8] = *(const int4*)&Whl[(size_t)n * 128 + c * 8];
    }
    int wv = tid >> 6, lane = tid & 63;
    int q = lane >> 4, r15 = lane & 15;
    half8 afrag[4];
    int nodeA = n0 + wv * 16 + r15;
#pragma unroll
    for (int s = 0; s < 4; ++s)
        afrag[s] = *(const half8*)&P[(size_t)nodeA * HIDD + s * 32 + q * 8];
    __syncthreads();
    f32x4 acc[8];
#pragma unroll
    for (int ct = 0; ct < 8; ++ct) {
        f32x4 c = {0.f, 0.f, 0.f, 0.f};
#pragma unroll
        for (int s = 0; s < 4; ++s) {
            half8 bfrag = *(const half8*)&w[(ct * 16 + r15) * 136 + s * 32 + q * 8];
            c = __builtin_amdgcn_mfma_f32_16x16x32_f16(afrag[s], bfrag, c, 0, 0, 0);
        }
        acc[ct] = c;
    }
    __syncthreads();
#pragma unroll
    for (int ct = 0; ct < 8; ++ct)
#pragma unroll
        for (int r = 0; r < 4; ++r)
            vv[(wv * 16 + q * 4 + r) * 132 + ct * 16 + r15] = acc[ct][r];
    __syncthreads();
    int grp = tid >> 4, sub = tid & 15;
    float4 bi0 = *(const float4*)&bias[sub * 8],  bi1 = *(const float4*)&bias[sub * 8 + 4];
    float4 g0  = *(const float4*)&gamma[sub * 8], g1  = *(const float4*)&gamma[sub * 8 + 4];
    float4 be0 = *(const float4*)&beta[sub * 8],  be1 = *(const float4*)&beta[sub * 8 + 4];
    float bi[8] = {bi0.x,bi0.y,bi0.z,bi0.w,bi1.x,bi1.y,bi1.z,bi1.w};
    float gg[8] = {g0.x,g0.y,g0.z,g0.w,g1.x,g1.y,g1.z,g1.w};
    float be[8] = {be0.x,be0.y,be0.z,be0.w,be1.x,be1.y,be1.z,be1.w};
    half_t tv[4][8];
#pragma unroll
    for (int pp = 0; pp < 4; ++pp) {
        int nl = grp + pp * 16;
        int node = n0 + nl;
        float v8[8];
        half8 hold = *(const half8*)&Hh[(size_t)node * HIDD + sub * 8];
#pragma unroll
        for (int j = 0; j < 8; ++j) v8[j] = vv[nl * 132 + sub * 8 + j] + bi[j] + (float)hold[j];
        float sum = 0.f;
#pragma unroll
        for (int j = 0; j < 8; ++j) sum += v8[j];
#pragma unroll
        for (int o = 8; o; o >>= 1) sum += __shfl_xor(sum, o);
        float mu = sum * (1.f / HIDD);
        float var = 0.f;
#pragma unroll
        for (int j = 0; j < 8; ++j) { float dx = v8[j] - mu; var += dx * dx; }
#pragma unroll
        for (int o = 8; o; o >>= 1) var += __shfl_xor(var, o);
        float rs = rsqrtf(var * (1.f / HIDD) + 1e-5f);
#pragma unroll
        for (int j = 0; j < 8; ++j)
            tv[pp][j] = (half_t)fmaxf((v8[j] - mu) * rs * gg[j] + be[j], 0.f);
    }
    __syncthreads();   // done reading vv; rewrite w region with T tile (136-pad half rows)
#pragma unroll
    for (int pp = 0; pp < 4; ++pp) {
        int nl = grp + pp * 16;
        union { int4 i4; half_t h[8]; } u;
#pragma unroll
        for (int j = 0; j < 8; ++j) u.h[j] = tv[pp][j];
        *(int4*)&w[nl * 136 + sub * 8] = u.i4;
    }
    __syncthreads();
    // predictor head (nodes of this block all belong to head n0>>9)
    int head = n0 >> 9;
    const half_t* W1g = W1h + (size_t)head * 64 * 128;
    half8 pa[4];
#pragma unroll
    for (int s = 0; s < 4; ++s)
        pa[s] = *(const half8*)&w[(wv * 16 + r15) * 136 + s * 32 + q * 8];
    float lg[3][4];
#pragma unroll
    for (int o = 0; o < 3; ++o)
#pragma unroll
        for (int r = 0; r < 4; ++r) lg[o][r] = 0.f;
#pragma unroll
    for (int ct2 = 0; ct2 < 4; ++ct2) {
        int n2 = ct2 * 16 + r15;
        f32x4 c = {0.f, 0.f, 0.f, 0.f};
#pragma unroll
        for (int s = 0; s < 4; ++s) {
            half8 bfrag = *(const half8*)&W1g[(size_t)n2 * 128 + s * 32 + q * 8];
            c = __builtin_amdgcn_mfma_f32_16x16x32_f16(pa[s], bfrag, c, 0, 0, 0);
        }
        float w2a = W2p[(size_t)head * 192 + n2 * 3 + 0];
        float w2b = W2p[(size_t)head * 192 + n2 * 3 + 1];
        float w2c = W2p[(size_t)head * 192 + n2 * 3 + 2];
#pragma unroll
        for (int r = 0; r < 4; ++r) {
            float t = fmaxf(c[r], 0.f);
            lg[0][r] += t * w2a;
            lg[1][r] += t * w2b;
            lg[2][r] += t * w2c;
        }
    }
#pragma unroll
    for (int o = 8; o; o >>= 1)
#pragma unroll
        for (int oo = 0; oo < 3; ++oo)
#pragma unroll
            for (int r = 0; r < 4; ++r) lg[oo][r] += __shfl_xor(lg[oo][r], o);
    if (r15 == 0) {
        int nodeD = n0 + wv * 16 + q * 4;
#pragma unroll
        for (int r = 0; r < 4; ++r) {
            float l0 = lg[0][r], l1 = lg[1][r], l2 = lg[2][r];
            float mx = fmaxf(l0, fmaxf(l1, l2));
            float e0 = __expf(l0 - mx), e1 = __expf(l1 - mx), e2 = __expf(l2 - mx);
            float inv = 1.f / (e0 + e1 + e2);
            float* op = out + (size_t)(nodeD + r) * OUTC;
            op[0] = e0 * inv; op[1] = e1 * inv; op[2] = e2 * inv;
        }
    }
}

extern "C" void kernel_launch(void* const* d_in, const int* in_sizes, int n_in,
                              void* d_out, int out_size, void* d_ws, size_t ws_size,
                              hipStream_t stream) {
    const float* x        = (const float*)d_in[0];
    const int*   ei       = (const int*)d_in[1];
    const float* W0       = (const float*)d_in[2];
    const float* att_src0 = (const float*)d_in[3];
    const float* att_dst0 = (const float*)d_in[4];
    const float* bias0    = (const float*)d_in[5];
    const float* W_res    = (const float*)d_in[6];
    const float* as_res   = (const float*)d_in[7];
    const float* ad_res   = (const float*)d_in[8];
    const float* b_res    = (const float*)d_in[9];
    const float* gamma    = (const float*)d_in[10];
    const float* beta     = (const float*)d_in[11];
    const float* W1p      = (const float*)d_in[12];
    const float* W2p      = (const float*)d_in[13];
    float* out = (float*)d_out;

    int E = in_sizes[1] / 2;
    int Etot = E + NND;

    char* p = (char*)d_ws;
    auto alloc = [&](size_t bytes) { void* r = (void*)p; p += (bytes + 255) & ~(size_t)255; return r; };
    int*    counts  = (int*)alloc((size_t)NND * 4);
    int*    off     = (int*)alloc((size_t)(NND + 1) * 4);
    int*    rank    = (int*)alloc((size_t)Etot * 4);
    int*    csr_src = (int*)alloc((size_t)Etot * 4);
    half_t* xh      = (half_t*)alloc((size_t)NND * 32 * 2);
    half_t* Pbuf    = (half_t*)alloc((size_t)NND * HIDD * 2);
    unsigned char* Th8 = (unsigned char*)alloc((size_t)NND * HIDD);
    half_t* Hh      = (half_t*)alloc((size_t)NND * HIDD * 2);
    float*  a_s     = (float*)alloc((size_t)NND * 4);
    float*  a_d     = (float*)alloc((size_t)NND * 4);
    half_t* Wh      = (half_t*)alloc((size_t)4 * HIDD * HIDD * 2);
    half_t* W1h     = (half_t*)alloc((size_t)NHEAD * 64 * HIDD * 2);
    half_t* W0t     = (half_t*)alloc((size_t)HIDD * 32 * 2);
    float*  wvec    = (float*)alloc((size_t)1280 * 4);

    int egrid = (Etot + 255) / 256;

    hipMemsetAsync(counts, 0, (size_t)NND * 4, stream);
    prep_kernel<<<1090 + egrid, 256, 0, stream>>>(W0, W_res, W1p, att_src0, att_dst0,
        as_res, ad_res, x, ei, E, Wh, W1h, W0t, wvec, xh, counts, rank);
    scan_kernel<<<1, 1024, 0, stream>>>(counts, off);
    fill_a0_kernel<<<egrid + 512, 256, 0, stream>>>(ei, E, egrid, off, rank, csr_src,
                                                    xh, wvec, a_s, a_d);

    // layer 0
    agg0_kernel<<<NND / 4, 256, 0, stream>>>(xh, a_s, a_d, csr_src, off, Pbuf);
    gemm_kernel<32, false><<<NND / 64, 256, 0, stream>>>(Pbuf, W0t, bias0, Hh, Th8,
        gamma, beta, wvec + 128, wvec + 640 + 128, a_s, a_d);

    // res blocks 0..2
    for (int i = 0; i < 3; ++i) {
        agg_kernel<<<NND / 4, 256, 0, stream>>>(Th8, a_s, a_d, csr_src, off, Pbuf);
        gemm_kernel<128, true><<<NND / 64, 256, 0, stream>>>(Pbuf, Wh + (size_t)i * 16384,
            b_res + i * HIDD, Hh, Th8,
            gamma + (i + 1) * HIDD, beta + (i + 1) * HIDD,
            wvec + (i + 2) * 128, wvec + 640 + (i + 2) * 128, a_s, a_d);
    }

    // res block 3 + final LN + predictor + softmax
    agg_kernel<<<NND / 4, 256, 0, stream>>>(Th8, a_s, a_d, csr_src, off, Pbuf);
    gemm_last_kernel<<<NND / 64, 256, 0, stream>>>(Pbuf, Wh + (size_t)3 * 16384,
        b_res + 3 * HIDD, Hh, gamma, beta, W1h, W2p, out);
}